// Round 1
// baseline (1210.088 us; speedup 1.0000x reference)
//
#include <hip/hip_runtime.h>
#include <hip/hip_bf16.h>

// ===========================================================================
// Decoder layer: RMSNorm -> QKV(+head RMSNorm+RoPE) -> GQA attn with R=128
// virtual KV tokens -> Wo + residual -> RMSNorm -> SwiGLU MLP -> residual.
// All GEMMs bf16 MFMA (16x16x32), fp32 accumulate. d_ws usage ~194 MB.
// ===========================================================================

#define DEV __device__ __forceinline__

using f32x4  = __attribute__((ext_vector_type(4))) float;
using bf16x8 = __attribute__((ext_vector_type(8))) short;

constexpr int B_ = 2, T_ = 2048, D_ = 2048, H_ = 16, HKV_ = 8, HD_ = 128;
constexpr int R_ = 128, DFF_ = 6144, TK_ = R_ + T_;   // TK_=2176
constexpr float EPS_ = 1e-6f;
constexpr float SCALING_ = 0.08838834764831845f;      // 128^-0.5

DEV float bf2f(unsigned short u) {
  unsigned int x = ((unsigned int)u) << 16;
  return __builtin_bit_cast(float, x);
}
DEV unsigned short f2bf(float f) {
  unsigned int x = __builtin_bit_cast(unsigned int, f);
  x += 0x7fffu + ((x >> 16) & 1u);   // RNE
  return (unsigned short)(x >> 16);
}

// ---------------------------------------------------------------------------
// RMSNorm (fp32 in, bf16 out). One block per row of D=2048, 256 thr x 8 elem.
// ---------------------------------------------------------------------------
__global__ __launch_bounds__(256) void k_rmsnorm(const float* __restrict__ x,
                                                 const float* __restrict__ w,
                                                 unsigned short* __restrict__ out) {
  const int row = blockIdx.x;
  const float* xr = x + (size_t)row * D_;
  const int t8 = threadIdx.x * 8;
  float4 a = *(const float4*)(xr + t8);
  float4 b = *(const float4*)(xr + t8 + 4);
  float ss = a.x*a.x + a.y*a.y + a.z*a.z + a.w*a.w
           + b.x*b.x + b.y*b.y + b.z*b.z + b.w*b.w;
  #pragma unroll
  for (int m = 1; m < 64; m <<= 1) ss += __shfl_xor(ss, m);
  __shared__ float red[4];
  if ((threadIdx.x & 63) == 0) red[threadIdx.x >> 6] = ss;
  __syncthreads();
  ss = red[0] + red[1] + red[2] + red[3];
  const float sc = rsqrtf(ss * (1.0f / D_) + EPS_);
  float4 wa = *(const float4*)(w + t8);
  float4 wb = *(const float4*)(w + t8 + 4);
  bf16x8 ov;
  ov[0] = (short)f2bf(a.x * sc * wa.x); ov[1] = (short)f2bf(a.y * sc * wa.y);
  ov[2] = (short)f2bf(a.z * sc * wa.z); ov[3] = (short)f2bf(a.w * sc * wa.w);
  ov[4] = (short)f2bf(b.x * sc * wb.x); ov[5] = (short)f2bf(b.y * sc * wb.y);
  ov[6] = (short)f2bf(b.z * sc * wb.z); ov[7] = (short)f2bf(b.w * sc * wb.w);
  *(bf16x8*)(out + (size_t)row * D_ + t8) = ov;
}

// ---------------------------------------------------------------------------
// Weight transpose+convert: W (K,N) fp32 row-major -> Wt (N,K) bf16 row-major.
// 32x32 tiles via LDS.
// ---------------------------------------------------------------------------
__global__ __launch_bounds__(256) void k_wtrans(const float* __restrict__ W,
                                                unsigned short* __restrict__ Wt,
                                                int K, int N) {
  __shared__ float tile[32][33];
  const int n0 = blockIdx.x * 32, k0 = blockIdx.y * 32;
  {
    const int kl = threadIdx.x >> 3, nc = (threadIdx.x & 7) * 4;
    float4 f = *(const float4*)(W + (size_t)(k0 + kl) * N + n0 + nc);
    tile[kl][nc] = f.x; tile[kl][nc + 1] = f.y;
    tile[kl][nc + 2] = f.z; tile[kl][nc + 3] = f.w;
  }
  __syncthreads();
  const int nl = threadIdx.x >> 3, kc = (threadIdx.x & 7) * 4;
  ushort4 o;
  o.x = f2bf(tile[kc][nl]);     o.y = f2bf(tile[kc + 1][nl]);
  o.z = f2bf(tile[kc + 2][nl]); o.w = f2bf(tile[kc + 3][nl]);
  *(ushort4*)(Wt + (size_t)(n0 + nl) * K + k0 + kc) = o;
}

// ---------------------------------------------------------------------------
// GEMM: C(M,N) = A(M,K) @ Bt(N,K)^T, bf16 inputs, fp32 accum.
// 128x128 tile, BK=64, 4 waves (2x2), 4x4 16x16x32 frags/wave.
// XOR-swizzled LDS (byte ^= (row&7)<<4) for conflict-balanced ds_read_b128.
// EPI=0: bf16 out. EPI=1: fp32 out = acc + resid.
// ---------------------------------------------------------------------------
template <int EPI>
__global__ __launch_bounds__(256) void k_gemm(const unsigned short* __restrict__ A,
                                              const unsigned short* __restrict__ Bt,
                                              void* __restrict__ Cp,
                                              const float* __restrict__ resid,
                                              int M, int N, int K) {
  __shared__ unsigned short lA[128 * 64];
  __shared__ unsigned short lB[128 * 64];
  const int tid = threadIdx.x;
  const int lane = tid & 63;
  const int wave = tid >> 6;
  const int wm = wave >> 1, wn = wave & 1;
  const int row0 = blockIdx.y * 128, col0 = blockIdx.x * 128;
  const int sr = tid & 127;
  const int sc = (tid >> 7) * 32;   // element col base for staging
  const unsigned short* pa = A  + (size_t)(row0 + sr) * K + sc;
  const unsigned short* pb = Bt + (size_t)(col0 + sr) * K + sc;
  char* lAc = (char*)lA;
  char* lBc = (char*)lB;
  const int sbase = sr * 128 + sc * 2;
  const int swzS = (sr & 7) << 4;

  f32x4 zero = {0.f, 0.f, 0.f, 0.f};
  f32x4 acc[4][4];
  #pragma unroll
  for (int i = 0; i < 4; i++)
    #pragma unroll
    for (int j = 0; j < 4; j++) acc[i][j] = zero;

  for (int k0 = 0; k0 < K; k0 += 64) {
    bf16x8 a0 = *(const bf16x8*)(pa);      bf16x8 a1 = *(const bf16x8*)(pa + 8);
    bf16x8 a2 = *(const bf16x8*)(pa + 16); bf16x8 a3 = *(const bf16x8*)(pa + 24);
    bf16x8 b0 = *(const bf16x8*)(pb);      bf16x8 b1 = *(const bf16x8*)(pb + 8);
    bf16x8 b2 = *(const bf16x8*)(pb + 16); bf16x8 b3 = *(const bf16x8*)(pb + 24);
    *(bf16x8*)(lAc + ((sbase)      ^ swzS)) = a0;
    *(bf16x8*)(lAc + ((sbase + 16) ^ swzS)) = a1;
    *(bf16x8*)(lAc + ((sbase + 32) ^ swzS)) = a2;
    *(bf16x8*)(lAc + ((sbase + 48) ^ swzS)) = a3;
    *(bf16x8*)(lBc + ((sbase)      ^ swzS)) = b0;
    *(bf16x8*)(lBc + ((sbase + 16) ^ swzS)) = b1;
    *(bf16x8*)(lBc + ((sbase + 32) ^ swzS)) = b2;
    *(bf16x8*)(lBc + ((sbase + 48) ^ swzS)) = b3;
    __syncthreads();
    #pragma unroll
    for (int kc = 0; kc < 2; ++kc) {
      bf16x8 af[4], bfr[4];
      #pragma unroll
      for (int i = 0; i < 4; i++) {
        const int ra = wm * 64 + i * 16 + (lane & 15);
        af[i]  = *(const bf16x8*)(lAc + ((ra * 128 + kc * 64 + (lane >> 4) * 16) ^ ((ra & 7) << 4)));
        const int rb = wn * 64 + i * 16 + (lane & 15);
        bfr[i] = *(const bf16x8*)(lBc + ((rb * 128 + kc * 64 + (lane >> 4) * 16) ^ ((rb & 7) << 4)));
      }
      #pragma unroll
      for (int mi = 0; mi < 4; mi++)
        #pragma unroll
        for (int ni = 0; ni < 4; ni++)
          acc[mi][ni] = __builtin_amdgcn_mfma_f32_16x16x32_bf16(af[mi], bfr[ni], acc[mi][ni], 0, 0, 0);
    }
    __syncthreads();
    pa += 64;
    pb += 64;
  }

  const int crow = row0 + wm * 64 + ((lane >> 4) * 4);
  const int ccol = col0 + wn * 64 + (lane & 15);
  #pragma unroll
  for (int mi = 0; mi < 4; mi++)
    #pragma unroll
    for (int ni = 0; ni < 4; ni++) {
      const int r = crow + mi * 16;
      const int c = ccol + ni * 16;
      if constexpr (EPI == 0) {
        unsigned short* C = (unsigned short*)Cp;
        #pragma unroll
        for (int j = 0; j < 4; j++) C[(size_t)(r + j) * N + c] = f2bf(acc[mi][ni][j]);
      } else {
        float* C = (float*)Cp;
        #pragma unroll
        for (int j = 0; j < 4; j++)
          C[(size_t)(r + j) * N + c] = acc[mi][ni][j] + resid[(size_t)(r + j) * N + c];
      }
    }
}

// ---------------------------------------------------------------------------
// Per-head RMSNorm + RoPE. in: (B,T,NH,HD) bf16 GEMM output.
// ISQ=1 -> q_rope (B,H,T,HD); ISQ=0 -> k_all[(B,HKV,TK)] rows R..R+T-1.
// ---------------------------------------------------------------------------
template <int ISQ>
__global__ __launch_bounds__(128) void k_qknorm(const unsigned short* __restrict__ in,
                                                const float* __restrict__ nw,
                                                const float* __restrict__ cosT,
                                                const float* __restrict__ sinT,
                                                unsigned short* __restrict__ out) {
  const int t = blockIdx.x, hh = blockIdx.y, b = blockIdx.z;
  const int NH = ISQ ? H_ : HKV_;
  const int hd = threadIdx.x;
  float v = bf2f(in[(((size_t)b * T_ + t) * NH + hh) * HD_ + hd]);
  float ss = v * v;
  #pragma unroll
  for (int m = 1; m < 64; m <<= 1) ss += __shfl_xor(ss, m);
  __shared__ float red[2];
  __shared__ float buf[128];
  if ((hd & 63) == 0) red[hd >> 6] = ss;
  __syncthreads();
  ss = red[0] + red[1];
  const float nv = v * rsqrtf(ss * (1.0f / HD_) + EPS_) * nw[hd];
  buf[hd] = nv;
  __syncthreads();
  const float rot = hd < 64 ? -buf[hd + 64] : buf[hd - 64];
  const float o = nv * cosT[(size_t)t * HD_ + hd] + rot * sinT[(size_t)t * HD_ + hd];
  if (ISQ) out[(((size_t)b * H_ + hh) * T_ + t) * HD_ + hd] = f2bf(o);
  else     out[(((size_t)b * HKV_ + hh) * TK_ + R_ + t) * HD_ + hd] = f2bf(o);
}

// ---------------------------------------------------------------------------
// Virtual K rows: k_all[.., 0..R-1, ..] = k_extra * eff  (eff = 0.5*sigmoid(a))
// ---------------------------------------------------------------------------
__global__ __launch_bounds__(256) void k_kvirt(const float* __restrict__ ke,
                                               const float* __restrict__ alog,
                                               unsigned short* __restrict__ k_all) {
  const size_t i = (size_t)blockIdx.x * 256 + threadIdx.x;  // B*HKV*R*HD = 262144
  const float eff = 0.5f / (1.f + __expf(-alog[0]));
  const int hd = (int)(i & 127);
  const int r  = (int)((i >> 7) & 127);
  const int bk = (int)(i >> 14);
  k_all[((size_t)bk * TK_ + r) * HD_ + hd] = f2bf(ke[i] * eff);
}

// ---------------------------------------------------------------------------
// Build v_allT (B,HKV,HD,TK) bf16 = transpose of [v_extra*eff ; v]  (32x32 LDS)
// ---------------------------------------------------------------------------
__global__ __launch_bounds__(256) void k_vbuild(const unsigned short* __restrict__ vbuf,
                                                const float* __restrict__ ve,
                                                const float* __restrict__ alog,
                                                unsigned short* __restrict__ vT) {
  __shared__ float tile[32][33];
  const int kt = blockIdx.x, ht = blockIdx.y, bk = blockIdx.z;
  const int b = bk >> 3, kvh = bk & 7;
  const float eff = 0.5f / (1.f + __expf(-alog[0]));
  const int kl = threadIdx.x >> 3, hc = (threadIdx.x & 7) * 4;
  const int key = kt * 32 + kl, hd0 = ht * 32;
  if (key < R_) {
    float4 f = *(const float4*)(ve + (((size_t)(b * HKV_ + kvh) * R_ + key) * HD_ + hd0 + hc));
    tile[kl][hc] = f.x * eff; tile[kl][hc + 1] = f.y * eff;
    tile[kl][hc + 2] = f.z * eff; tile[kl][hc + 3] = f.w * eff;
  } else {
    const unsigned short* s = vbuf + (((size_t)(b * T_ + key - R_) * HKV_ + kvh) * HD_ + hd0 + hc);
    ushort4 u = *(const ushort4*)s;
    tile[kl][hc] = bf2f(u.x); tile[kl][hc + 1] = bf2f(u.y);
    tile[kl][hc + 2] = bf2f(u.z); tile[kl][hc + 3] = bf2f(u.w);
  }
  __syncthreads();
  const int hl = threadIdx.x >> 3, kc = (threadIdx.x & 7) * 4;
  ushort4 o;
  o.x = f2bf(tile[kc][hl]);     o.y = f2bf(tile[kc + 1][hl]);
  o.z = f2bf(tile[kc + 2][hl]); o.w = f2bf(tile[kc + 3][hl]);
  *(ushort4*)(vT + ((size_t)bk * HD_ + hd0 + hl) * TK_ + kt * 32 + kc) = o;
}

// ---------------------------------------------------------------------------
// Flash attention. Block: 256 thr (4 waves), 64 q-rows (16/wave), 64-key tiles.
// Causal + R virtual tokens (always visible). Online softmax per wave.
// ---------------------------------------------------------------------------
__global__ __launch_bounds__(256) void k_attn(const unsigned short* __restrict__ qr,
                                              const unsigned short* __restrict__ k_all,
                                              const unsigned short* __restrict__ v_allT,
                                              unsigned short* __restrict__ out) {
  __shared__ unsigned short kT[64 * 128];   // [key][hd], swizzled
  __shared__ unsigned short vS[128 * 64];   // [hd][key], swizzled
  __shared__ unsigned short pS[4][16 * 64]; // per-wave P, swizzled
  const int tid = threadIdx.x, lane = tid & 63, w = tid >> 6;
  const int qb = blockIdx.x, h = blockIdx.y, b = blockIdx.z;
  const int kvh = h >> 1;   // G = 2
  const int q0 = qb * 64;

  // Q fragments straight from global (rows are this wave's 16 q-rows)
  const unsigned short* qbase =
      qr + ((size_t)((b * H_ + h) * T_) + q0 + w * 16 + (lane & 15)) * HD_ + (lane >> 4) * 8;
  bf16x8 qf[4];
  #pragma unroll
  for (int kc = 0; kc < 4; kc++) qf[kc] = *(const bf16x8*)(qbase + kc * 32);

  f32x4 zero = {0.f, 0.f, 0.f, 0.f};
  f32x4 o[8];
  #pragma unroll
  for (int i = 0; i < 8; i++) o[i] = zero;
  float mrow[4], lrow[4];
  #pragma unroll
  for (int j = 0; j < 4; j++) { mrow[j] = -3e38f; lrow[j] = 0.f; }

  const unsigned short* kaBase = k_all  + (size_t)(b * HKV_ + kvh) * TK_ * HD_;
  const unsigned short* vaBase = v_allT + (size_t)(b * HKV_ + kvh) * HD_ * TK_;
  const int ntiles = qb + 3;
  const int kr = tid >> 2,  kq = (tid & 3) * 32;    // kT staging coords
  const int vr = tid & 127, vq = (tid >> 7) * 32;   // vS staging coords
  char* kTc = (char*)kT;
  char* vSc = (char*)vS;

  for (int it = 0; it < ntiles; ++it) {
    const int ks = it * 64;
    {
      const unsigned short* src = kaBase + (size_t)(ks + kr) * HD_ + kq;
      const int base = kr * 256 + kq * 2, swz = (kr & 7) << 4;
      #pragma unroll
      for (int c = 0; c < 4; c++)
        *(bf16x8*)(kTc + ((base + c * 16) ^ swz)) = *(const bf16x8*)(src + c * 8);
    }
    {
      const unsigned short* src = vaBase + (size_t)vr * TK_ + ks + vq;
      const int base = vr * 128 + vq * 2, swz = (vr & 7) << 4;
      #pragma unroll
      for (int c = 0; c < 4; c++)
        *(bf16x8*)(vSc + ((base + c * 16) ^ swz)) = *(const bf16x8*)(src + c * 8);
    }
    __syncthreads();

    // S = Q K^T (16 rows x 64 keys per wave)
    f32x4 s[4];
    #pragma unroll
    for (int ni = 0; ni < 4; ni++) {
      f32x4 a = zero;
      const int rk = ni * 16 + (lane & 15);
      #pragma unroll
      for (int kc = 0; kc < 4; kc++) {
        bf16x8 kf = *(const bf16x8*)(kTc + ((rk * 256 + kc * 64 + (lane >> 4) * 16) ^ ((rk & 7) << 4)));
        a = __builtin_amdgcn_mfma_f32_16x16x32_bf16(qf[kc], kf, a, 0, 0, 0);
      }
      s[ni] = a;
    }

    // scale + causal mask (only the diagonal tile needs masking)
    const bool diag = (it == ntiles - 1);
    #pragma unroll
    for (int ni = 0; ni < 4; ni++)
      #pragma unroll
      for (int j = 0; j < 4; j++) {
        float v = s[ni][j] * SCALING_;
        if (diag) {
          const int cl = ni * 16 + (lane & 15);
          const int rl = w * 16 + (lane >> 4) * 4 + j;
          if (cl > rl) v = -3e38f;
        }
        s[ni][j] = v;
      }

    // online softmax (rows live in 16-lane groups)
    float scl[4];
    #pragma unroll
    for (int j = 0; j < 4; j++) {
      float pm = fmaxf(fmaxf(s[0][j], s[1][j]), fmaxf(s[2][j], s[3][j]));
      #pragma unroll
      for (int m = 1; m < 16; m <<= 1) pm = fmaxf(pm, __shfl_xor(pm, m));
      const float mn = fmaxf(mrow[j], pm);
      scl[j] = __expf(mrow[j] - mn);
      mrow[j] = mn;
      float rs = 0.f;
      #pragma unroll
      for (int ni = 0; ni < 4; ni++) {
        const float p = __expf(s[ni][j] - mn);
        s[ni][j] = p;
        rs += p;
      }
      #pragma unroll
      for (int m = 1; m < 16; m <<= 1) rs += __shfl_xor(rs, m);
      lrow[j] = lrow[j] * scl[j] + rs;
    }
    #pragma unroll
    for (int ni = 0; ni < 8; ni++)
      #pragma unroll
      for (int j = 0; j < 4; j++) o[ni][j] *= scl[j];

    // P -> LDS (bf16, swizzled), then PV
    unsigned short* pw = pS[w];
    #pragma unroll
    for (int ni = 0; ni < 4; ni++)
      #pragma unroll
      for (int j = 0; j < 4; j++) {
        const int prow = (lane >> 4) * 4 + j;
        const int boff = (prow * 128 + (ni * 16 + (lane & 15)) * 2) ^ ((prow & 7) << 4);
        *(unsigned short*)((char*)pw + boff) = f2bf(s[ni][j]);
      }
    #pragma unroll
    for (int kk = 0; kk < 2; kk++) {
      const int pr = lane & 15;
      bf16x8 pa = *(const bf16x8*)((char*)pw + ((pr * 128 + kk * 64 + (lane >> 4) * 16) ^ ((pr & 7) << 4)));
      #pragma unroll
      for (int ni = 0; ni < 8; ni++) {
        const int rv = ni * 16 + (lane & 15);
        bf16x8 vb = *(const bf16x8*)(vSc + ((rv * 128 + kk * 64 + (lane >> 4) * 16) ^ ((rv & 7) << 4)));
        o[ni] = __builtin_amdgcn_mfma_f32_16x16x32_bf16(pa, vb, o[ni], 0, 0, 0);
      }
    }
    __syncthreads();
  }

  // out (B,T,H*HD) bf16
  const size_t orow = ((size_t)b * T_ + q0 + w * 16 + (lane >> 4) * 4) * (H_ * HD_)
                      + h * HD_ + (lane & 15);
  #pragma unroll
  for (int ni = 0; ni < 8; ni++)
    #pragma unroll
    for (int j = 0; j < 4; j++)
      out[orow + (size_t)j * (H_ * HD_) + ni * 16] = f2bf(o[ni][j] / lrow[j]);
}

// ---------------------------------------------------------------------------
// act = silu(g) * u, in place into g. 8 bf16 per thread.
// ---------------------------------------------------------------------------
__global__ __launch_bounds__(256) void k_silumul(unsigned short* __restrict__ g,
                                                 const unsigned short* __restrict__ u) {
  const size_t i = ((size_t)blockIdx.x * 256 + threadIdx.x) * 8;
  bf16x8 gv = *(bf16x8*)(g + i);
  bf16x8 uv = *(const bf16x8*)(u + i);
  bf16x8 ov;
  #pragma unroll
  for (int j = 0; j < 8; j++) {
    const float x = bf2f((unsigned short)gv[j]);
    const float y = bf2f((unsigned short)uv[j]);
    ov[j] = (short)f2bf(x / (1.f + __expf(-x)) * y);
  }
  *(bf16x8*)(g + i) = ov;
}

// ===========================================================================
extern "C" void kernel_launch(void* const* d_in, const int* in_sizes, int n_in,
                              void* d_out, int out_size, void* d_ws, size_t ws_size,
                              hipStream_t stream) {
  const float* hs   = (const float*)d_in[0];
  const float* ke   = (const float*)d_in[1];
  const float* ve   = (const float*)d_in[2];
  const float* cosT = (const float*)d_in[3];
  const float* sinT = (const float*)d_in[4];
  // d_in[5] = attention_mask: deterministic causal, applied analytically.
  const float* alog = (const float*)d_in[6];
  const float* Wq   = (const float*)d_in[7];
  const float* Wk   = (const float*)d_in[8];
  const float* Wv   = (const float*)d_in[9];
  const float* Wo   = (const float*)d_in[10];
  const float* qnw  = (const float*)d_in[11];
  const float* knw  = (const float*)d_in[12];
  const float* ln1  = (const float*)d_in[13];
  const float* ln2  = (const float*)d_in[14];
  const float* Wg   = (const float*)d_in[15];
  const float* Wu   = (const float*)d_in[16];
  const float* Wd   = (const float*)d_in[17];

  char* ws = (char*)d_ws;
  size_t off = 0;
  auto alloc = [&](size_t bytes) {
    void* p = ws + off;
    off += (bytes + 255) & ~(size_t)255;
    return p;
  };
  const int M = B_ * T_;  // 4096
  unsigned short* h     = (unsigned short*)alloc((size_t)M * D_ * 2);          // 16.78M (reused for h2)
  unsigned short* wt    = (unsigned short*)alloc((size_t)DFF_ * D_ * 2);       // 25.17M (weight buf, reused)
  unsigned short* qbuf  = (unsigned short*)alloc((size_t)M * 2048 * 2);        // 16.78M (later attn_out, later u)
  unsigned short* kbuf  = (unsigned short*)alloc((size_t)M * 1024 * 2);        // 8.39M
  unsigned short* vbuf  = (unsigned short*)alloc((size_t)M * 1024 * 2);        // 8.39M
  unsigned short* qrope = (unsigned short*)alloc((size_t)B_ * H_ * T_ * HD_ * 2);   // 16.78M
  unsigned short* kall  = (unsigned short*)alloc((size_t)B_ * HKV_ * TK_ * HD_ * 2);// 8.91M
  unsigned short* vallT = (unsigned short*)alloc((size_t)B_ * HKV_ * TK_ * HD_ * 2);// 8.91M
  float*          hidden= (float*)alloc((size_t)M * D_ * 4);                   // 33.55M
  unsigned short* g     = (unsigned short*)alloc((size_t)M * DFF_ * 2);        // 50.33M
  unsigned short* u     = qbuf;  // aliases [qbuf..qrope) = 50.34M, dead by the Wu GEMM

  // 1) input layernorm
  k_rmsnorm<<<M, 256, 0, stream>>>(hs, ln1, h);
  // 2) Q projection + head norm + RoPE
  k_wtrans<<<dim3(2048 / 32, 2048 / 32), 256, 0, stream>>>(Wq, wt, 2048, 2048);
  k_gemm<0><<<dim3(2048 / 128, M / 128), 256, 0, stream>>>(h, wt, qbuf, nullptr, M, 2048, 2048);
  k_qknorm<1><<<dim3(T_, H_, B_), 128, 0, stream>>>(qbuf, qnw, cosT, sinT, qrope);
  // 3) K projection + head norm + RoPE + virtual K
  k_wtrans<<<dim3(1024 / 32, 2048 / 32), 256, 0, stream>>>(Wk, wt, 2048, 1024);
  k_gemm<0><<<dim3(1024 / 128, M / 128), 256, 0, stream>>>(h, wt, kbuf, nullptr, M, 1024, 2048);
  k_qknorm<0><<<dim3(T_, HKV_, B_), 128, 0, stream>>>(kbuf, knw, cosT, sinT, kall);
  k_kvirt<<<(B_ * HKV_ * R_ * HD_) / 256, 256, 0, stream>>>(ke, alog, kall);
  // 4) V projection + transposed concat
  k_wtrans<<<dim3(1024 / 32, 2048 / 32), 256, 0, stream>>>(Wv, wt, 2048, 1024);
  k_gemm<0><<<dim3(1024 / 128, M / 128), 256, 0, stream>>>(h, wt, vbuf, nullptr, M, 1024, 2048);
  k_vbuild<<<dim3(TK_ / 32, HD_ / 32, B_ * HKV_), 256, 0, stream>>>(vbuf, ve, alog, vallT);
  // 5) attention
  k_attn<<<dim3(T_ / 64, H_, B_), 256, 0, stream>>>(qrope, kall, vallT, qbuf);
  // 6) output projection + residual
  k_wtrans<<<dim3(2048 / 32, 2048 / 32), 256, 0, stream>>>(Wo, wt, 2048, 2048);
  k_gemm<1><<<dim3(2048 / 128, M / 128), 256, 0, stream>>>(qbuf, wt, hidden, hs, M, 2048, 2048);
  // 7) post-attn layernorm
  k_rmsnorm<<<M, 256, 0, stream>>>(hidden, ln2, h);
  // 8) SwiGLU MLP + residual
  k_wtrans<<<dim3(DFF_ / 32, 2048 / 32), 256, 0, stream>>>(Wg, wt, 2048, DFF_);
  k_gemm<0><<<dim3(DFF_ / 128, M / 128), 256, 0, stream>>>(h, wt, g, nullptr, M, DFF_, 2048);
  k_wtrans<<<dim3(DFF_ / 32, 2048 / 32), 256, 0, stream>>>(Wu, wt, 2048, DFF_);
  k_gemm<0><<<dim3(DFF_ / 128, M / 128), 256, 0, stream>>>(h, wt, u, nullptr, M, DFF_, 2048);
  k_silumul<<<((size_t)M * DFF_ / 8) / 256, 256, 0, stream>>>(g, u);
  k_wtrans<<<dim3(2048 / 32, DFF_ / 32), 256, 0, stream>>>(Wd, wt, DFF_, 2048);
  k_gemm<1><<<dim3(2048 / 128, M / 128), 256, 0, stream>>>(g, wt, (float*)d_out, hidden, M, 2048, DFF_);
}

// Round 2
// 995.182 us; speedup vs baseline: 1.2159x; 1.2159x over previous
//
#include <hip/hip_runtime.h>
#include <hip/hip_bf16.h>

// ===========================================================================
// Decoder layer: RMSNorm -> QKV(+head RMSNorm+RoPE) -> GQA attn with R=128
// virtual KV tokens -> Wo + residual -> RMSNorm -> SwiGLU MLP -> residual.
// Round 2: GEMM uses global_load_lds width-16 (m97 structure) + XCD swizzle;
// silu*u fused into the Wu GEMM epilogue.
// ===========================================================================

#define DEV __device__ __forceinline__

using f32x4  = __attribute__((ext_vector_type(4))) float;
using bf16x8 = __attribute__((ext_vector_type(8))) short;

constexpr int B_ = 2, T_ = 2048, D_ = 2048, H_ = 16, HKV_ = 8, HD_ = 128;
constexpr int R_ = 128, DFF_ = 6144, TK_ = R_ + T_;   // TK_=2176
constexpr float EPS_ = 1e-6f;
constexpr float SCALING_ = 0.08838834764831845f;      // 128^-0.5

DEV float bf2f(unsigned short u) {
  unsigned int x = ((unsigned int)u) << 16;
  return __builtin_bit_cast(float, x);
}
DEV unsigned short f2bf(float f) {
  unsigned int x = __builtin_bit_cast(unsigned int, f);
  x += 0x7fffu + ((x >> 16) & 1u);   // RNE
  return (unsigned short)(x >> 16);
}

// async global -> LDS, 16B per lane. lds base must be wave-uniform; HW writes
// lane l at lds + l*16.
DEV void gload_lds16(const void* g, void* l) {
  __builtin_amdgcn_global_load_lds((__attribute__((address_space(1))) void*)(g),
                                   (__attribute__((address_space(3))) void*)(l),
                                   16, 0, 0);
}

// ---------------------------------------------------------------------------
// RMSNorm (fp32 in, bf16 out). One block per row of D=2048, 256 thr x 8 elem.
// ---------------------------------------------------------------------------
__global__ __launch_bounds__(256) void k_rmsnorm(const float* __restrict__ x,
                                                 const float* __restrict__ w,
                                                 unsigned short* __restrict__ out) {
  const int row = blockIdx.x;
  const float* xr = x + (size_t)row * D_;
  const int t8 = threadIdx.x * 8;
  float4 a = *(const float4*)(xr + t8);
  float4 b = *(const float4*)(xr + t8 + 4);
  float ss = a.x*a.x + a.y*a.y + a.z*a.z + a.w*a.w
           + b.x*b.x + b.y*b.y + b.z*b.z + b.w*b.w;
  #pragma unroll
  for (int m = 1; m < 64; m <<= 1) ss += __shfl_xor(ss, m);
  __shared__ float red[4];
  if ((threadIdx.x & 63) == 0) red[threadIdx.x >> 6] = ss;
  __syncthreads();
  ss = red[0] + red[1] + red[2] + red[3];
  const float sc = rsqrtf(ss * (1.0f / D_) + EPS_);
  float4 wa = *(const float4*)(w + t8);
  float4 wb = *(const float4*)(w + t8 + 4);
  bf16x8 ov;
  ov[0] = (short)f2bf(a.x * sc * wa.x); ov[1] = (short)f2bf(a.y * sc * wa.y);
  ov[2] = (short)f2bf(a.z * sc * wa.z); ov[3] = (short)f2bf(a.w * sc * wa.w);
  ov[4] = (short)f2bf(b.x * sc * wb.x); ov[5] = (short)f2bf(b.y * sc * wb.y);
  ov[6] = (short)f2bf(b.z * sc * wb.z); ov[7] = (short)f2bf(b.w * sc * wb.w);
  *(bf16x8*)(out + (size_t)row * D_ + t8) = ov;
}

// ---------------------------------------------------------------------------
// Weight transpose+convert: W (K,N) fp32 row-major -> Wt (N,K) bf16 row-major.
// ---------------------------------------------------------------------------
__global__ __launch_bounds__(256) void k_wtrans(const float* __restrict__ W,
                                                unsigned short* __restrict__ Wt,
                                                int K, int N) {
  __shared__ float tile[32][33];
  const int n0 = blockIdx.x * 32, k0 = blockIdx.y * 32;
  {
    const int kl = threadIdx.x >> 3, nc = (threadIdx.x & 7) * 4;
    float4 f = *(const float4*)(W + (size_t)(k0 + kl) * N + n0 + nc);
    tile[kl][nc] = f.x; tile[kl][nc + 1] = f.y;
    tile[kl][nc + 2] = f.z; tile[kl][nc + 3] = f.w;
  }
  __syncthreads();
  const int nl = threadIdx.x >> 3, kc = (threadIdx.x & 7) * 4;
  ushort4 o;
  o.x = f2bf(tile[kc][nl]);     o.y = f2bf(tile[kc + 1][nl]);
  o.z = f2bf(tile[kc + 2][nl]); o.w = f2bf(tile[kc + 3][nl]);
  *(ushort4*)(Wt + (size_t)(n0 + nl) * K + k0 + kc) = o;
}

// ---------------------------------------------------------------------------
// GEMM: C(M,N) = A(M,K) @ Bt(N,K)^T, bf16 in, fp32 accum. 128x128 tile, BK=64,
// 4 waves (2x2), 4x4 16x16x32 frags. global_load_lds width-16 staging (m97).
// EPI=0: bf16 out. EPI=1: fp32 out = acc + resid. EPI=2: bf16 = silu(gmul)*acc.
// ---------------------------------------------------------------------------
template <int EPI>
__global__ __launch_bounds__(256) void k_gemm(const unsigned short* __restrict__ A,
                                              const unsigned short* __restrict__ Bt,
                                              void* __restrict__ Cp,
                                              const float* __restrict__ resid,
                                              const unsigned short* __restrict__ gmul,
                                              int M, int N, int K) {
  __shared__ __align__(16) unsigned short lA[128 * 64];
  __shared__ __align__(16) unsigned short lB[128 * 64];
  const int tid = threadIdx.x;
  const int lane = tid & 63;
  const int wave = tid >> 6;
  const int wm = wave >> 1, wn = wave & 1;

  // XCD-aware bijective swizzle (nwg % 8 == 0 for all our shapes)
  const int nbx = (int)gridDim.x;
  const int nwg = nbx * (int)gridDim.y;
  int bid = (int)blockIdx.y * nbx + (int)blockIdx.x;
  if ((nwg & 7) == 0) bid = (bid & 7) * (nwg >> 3) + (bid >> 3);
  const int row0 = (bid / nbx) * 128, col0 = (bid % nbx) * 128;

  // staging map: instr i, wave w, lane l -> LDS byte i*4096 + w*1024 + l*16
  //   => tile row r = i*32 + w*8 + (l>>3), col8 = l&7  (linear [128][64] bf16)
  const int srw = wave * 8 + (lane >> 3);
  const unsigned short* pa = A  + (size_t)(row0 + srw) * K + (lane & 7) * 8;
  const unsigned short* pb = Bt + (size_t)(col0 + srw) * K + (lane & 7) * 8;
  char* lAc = (char*)lA;
  char* lBc = (char*)lB;
  const int ldsw = wave * 1024;

  f32x4 zero = {0.f, 0.f, 0.f, 0.f};
  f32x4 acc[4][4];
  #pragma unroll
  for (int i = 0; i < 4; i++)
    #pragma unroll
    for (int j = 0; j < 4; j++) acc[i][j] = zero;

  for (int k0 = 0; k0 < K; k0 += 64) {
    #pragma unroll
    for (int i = 0; i < 4; i++) {
      gload_lds16(pa + (size_t)i * 32 * K, lAc + ldsw + i * 4096);
      gload_lds16(pb + (size_t)i * 32 * K, lBc + ldsw + i * 4096);
    }
    __syncthreads();   // compiler drains vmcnt(0) before s_barrier
    #pragma unroll
    for (int kc = 0; kc < 2; ++kc) {
      bf16x8 af[4], bfr[4];
      #pragma unroll
      for (int i = 0; i < 4; i++) {
        const int ra = wm * 64 + i * 16 + (lane & 15);
        af[i]  = *(const bf16x8*)(lAc + ra * 128 + kc * 64 + (lane >> 4) * 16);
        const int rb = wn * 64 + i * 16 + (lane & 15);
        bfr[i] = *(const bf16x8*)(lBc + rb * 128 + kc * 64 + (lane >> 4) * 16);
      }
      #pragma unroll
      for (int mi = 0; mi < 4; mi++)
        #pragma unroll
        for (int ni = 0; ni < 4; ni++)
          acc[mi][ni] = __builtin_amdgcn_mfma_f32_16x16x32_bf16(af[mi], bfr[ni], acc[mi][ni], 0, 0, 0);
    }
    __syncthreads();
    pa += 64;
    pb += 64;
  }

  const int crow = row0 + wm * 64 + ((lane >> 4) * 4);
  const int ccol = col0 + wn * 64 + (lane & 15);
  #pragma unroll
  for (int mi = 0; mi < 4; mi++)
    #pragma unroll
    for (int ni = 0; ni < 4; ni++) {
      const int r = crow + mi * 16;
      const int c = ccol + ni * 16;
      if constexpr (EPI == 0) {
        unsigned short* C = (unsigned short*)Cp;
        #pragma unroll
        for (int j = 0; j < 4; j++) C[(size_t)(r + j) * N + c] = f2bf(acc[mi][ni][j]);
      } else if constexpr (EPI == 1) {
        float* C = (float*)Cp;
        #pragma unroll
        for (int j = 0; j < 4; j++)
          C[(size_t)(r + j) * N + c] = acc[mi][ni][j] + resid[(size_t)(r + j) * N + c];
      } else {
        unsigned short* C = (unsigned short*)Cp;
        #pragma unroll
        for (int j = 0; j < 4; j++) {
          const float gx = bf2f(gmul[(size_t)(r + j) * N + c]);
          C[(size_t)(r + j) * N + c] = f2bf(gx / (1.f + __expf(-gx)) * acc[mi][ni][j]);
        }
      }
    }
}

// ---------------------------------------------------------------------------
// Per-head RMSNorm + RoPE. in: (B,T,NH,HD) bf16 GEMM output.
// ISQ=1 -> q_rope (B,H,T,HD); ISQ=0 -> k_all[(B,HKV,TK)] rows R..R+T-1.
// ---------------------------------------------------------------------------
template <int ISQ>
__global__ __launch_bounds__(128) void k_qknorm(const unsigned short* __restrict__ in,
                                                const float* __restrict__ nw,
                                                const float* __restrict__ cosT,
                                                const float* __restrict__ sinT,
                                                unsigned short* __restrict__ out) {
  const int t = blockIdx.x, hh = blockIdx.y, b = blockIdx.z;
  const int NH = ISQ ? H_ : HKV_;
  const int hd = threadIdx.x;
  float v = bf2f(in[(((size_t)b * T_ + t) * NH + hh) * HD_ + hd]);
  float ss = v * v;
  #pragma unroll
  for (int m = 1; m < 64; m <<= 1) ss += __shfl_xor(ss, m);
  __shared__ float red[2];
  __shared__ float buf[128];
  if ((hd & 63) == 0) red[hd >> 6] = ss;
  __syncthreads();
  ss = red[0] + red[1];
  const float nv = v * rsqrtf(ss * (1.0f / HD_) + EPS_) * nw[hd];
  buf[hd] = nv;
  __syncthreads();
  const float rot = hd < 64 ? -buf[hd + 64] : buf[hd - 64];
  const float o = nv * cosT[(size_t)t * HD_ + hd] + rot * sinT[(size_t)t * HD_ + hd];
  if (ISQ) out[(((size_t)b * H_ + hh) * T_ + t) * HD_ + hd] = f2bf(o);
  else     out[(((size_t)b * HKV_ + hh) * TK_ + R_ + t) * HD_ + hd] = f2bf(o);
}

// ---------------------------------------------------------------------------
// Virtual K rows: k_all[.., 0..R-1, ..] = k_extra * eff  (eff = 0.5*sigmoid(a))
// ---------------------------------------------------------------------------
__global__ __launch_bounds__(256) void k_kvirt(const float* __restrict__ ke,
                                               const float* __restrict__ alog,
                                               unsigned short* __restrict__ k_all) {
  const size_t i = (size_t)blockIdx.x * 256 + threadIdx.x;  // B*HKV*R*HD = 262144
  const float eff = 0.5f / (1.f + __expf(-alog[0]));
  const int hd = (int)(i & 127);
  const int r  = (int)((i >> 7) & 127);
  const int bk = (int)(i >> 14);
  k_all[((size_t)bk * TK_ + r) * HD_ + hd] = f2bf(ke[i] * eff);
}

// ---------------------------------------------------------------------------
// Build v_allT (B,HKV,HD,TK) bf16 = transpose of [v_extra*eff ; v]
// ---------------------------------------------------------------------------
__global__ __launch_bounds__(256) void k_vbuild(const unsigned short* __restrict__ vbuf,
                                                const float* __restrict__ ve,
                                                const float* __restrict__ alog,
                                                unsigned short* __restrict__ vT) {
  __shared__ float tile[32][33];
  const int kt = blockIdx.x, ht = blockIdx.y, bk = blockIdx.z;
  const int b = bk >> 3, kvh = bk & 7;
  const float eff = 0.5f / (1.f + __expf(-alog[0]));
  const int kl = threadIdx.x >> 3, hc = (threadIdx.x & 7) * 4;
  const int key = kt * 32 + kl, hd0 = ht * 32;
  if (key < R_) {
    float4 f = *(const float4*)(ve + (((size_t)(b * HKV_ + kvh) * R_ + key) * HD_ + hd0 + hc));
    tile[kl][hc] = f.x * eff; tile[kl][hc + 1] = f.y * eff;
    tile[kl][hc + 2] = f.z * eff; tile[kl][hc + 3] = f.w * eff;
  } else {
    const unsigned short* s = vbuf + (((size_t)(b * T_ + key - R_) * HKV_ + kvh) * HD_ + hd0 + hc);
    ushort4 u = *(const ushort4*)s;
    tile[kl][hc] = bf2f(u.x); tile[kl][hc + 1] = bf2f(u.y);
    tile[kl][hc + 2] = bf2f(u.z); tile[kl][hc + 3] = bf2f(u.w);
  }
  __syncthreads();
  const int hl = threadIdx.x >> 3, kc = (threadIdx.x & 7) * 4;
  ushort4 o;
  o.x = f2bf(tile[kc][hl]);     o.y = f2bf(tile[kc + 1][hl]);
  o.z = f2bf(tile[kc + 2][hl]); o.w = f2bf(tile[kc + 3][hl]);
  *(ushort4*)(vT + ((size_t)bk * HD_ + hd0 + hl) * TK_ + kt * 32 + kc) = o;
}

// ---------------------------------------------------------------------------
// Flash attention. Block: 256 thr (4 waves), 64 q-rows (16/wave), 64-key tiles.
// ---------------------------------------------------------------------------
__global__ __launch_bounds__(256) void k_attn(const unsigned short* __restrict__ qr,
                                              const unsigned short* __restrict__ k_all,
                                              const unsigned short* __restrict__ v_allT,
                                              unsigned short* __restrict__ out) {
  __shared__ unsigned short kT[64 * 128];   // [key][hd], swizzled
  __shared__ unsigned short vS[128 * 64];   // [hd][key], swizzled
  __shared__ unsigned short pS[4][16 * 64]; // per-wave P, swizzled
  const int tid = threadIdx.x, lane = tid & 63, w = tid >> 6;
  const int qb = blockIdx.x, h = blockIdx.y, b = blockIdx.z;
  const int kvh = h >> 1;   // G = 2
  const int q0 = qb * 64;

  const unsigned short* qbase =
      qr + ((size_t)((b * H_ + h) * T_) + q0 + w * 16 + (lane & 15)) * HD_ + (lane >> 4) * 8;
  bf16x8 qf[4];
  #pragma unroll
  for (int kc = 0; kc < 4; kc++) qf[kc] = *(const bf16x8*)(qbase + kc * 32);

  f32x4 zero = {0.f, 0.f, 0.f, 0.f};
  f32x4 o[8];
  #pragma unroll
  for (int i = 0; i < 8; i++) o[i] = zero;
  float mrow[4], lrow[4];
  #pragma unroll
  for (int j = 0; j < 4; j++) { mrow[j] = -3e38f; lrow[j] = 0.f; }

  const unsigned short* kaBase = k_all  + (size_t)(b * HKV_ + kvh) * TK_ * HD_;
  const unsigned short* vaBase = v_allT + (size_t)(b * HKV_ + kvh) * HD_ * TK_;
  const int ntiles = qb + 3;
  const int kr = tid >> 2,  kq = (tid & 3) * 32;
  const int vr = tid & 127, vq = (tid >> 7) * 32;
  char* kTc = (char*)kT;
  char* vSc = (char*)vS;

  for (int it = 0; it < ntiles; ++it) {
    const int ks = it * 64;
    {
      const unsigned short* src = kaBase + (size_t)(ks + kr) * HD_ + kq;
      const int base = kr * 256 + kq * 2, swz = (kr & 7) << 4;
      #pragma unroll
      for (int c = 0; c < 4; c++)
        *(bf16x8*)(kTc + ((base + c * 16) ^ swz)) = *(const bf16x8*)(src + c * 8);
    }
    {
      const unsigned short* src = vaBase + (size_t)vr * TK_ + ks + vq;
      const int base = vr * 128 + vq * 2, swz = (vr & 7) << 4;
      #pragma unroll
      for (int c = 0; c < 4; c++)
        *(bf16x8*)(vSc + ((base + c * 16) ^ swz)) = *(const bf16x8*)(src + c * 8);
    }
    __syncthreads();

    f32x4 s[4];
    #pragma unroll
    for (int ni = 0; ni < 4; ni++) {
      f32x4 a = zero;
      const int rk = ni * 16 + (lane & 15);
      #pragma unroll
      for (int kc = 0; kc < 4; kc++) {
        bf16x8 kf = *(const bf16x8*)(kTc + ((rk * 256 + kc * 64 + (lane >> 4) * 16) ^ ((rk & 7) << 4)));
        a = __builtin_amdgcn_mfma_f32_16x16x32_bf16(qf[kc], kf, a, 0, 0, 0);
      }
      s[ni] = a;
    }

    const bool diag = (it == ntiles - 1);
    #pragma unroll
    for (int ni = 0; ni < 4; ni++)
      #pragma unroll
      for (int j = 0; j < 4; j++) {
        float v = s[ni][j] * SCALING_;
        if (diag) {
          const int cl = ni * 16 + (lane & 15);
          const int rl = w * 16 + (lane >> 4) * 4 + j;
          if (cl > rl) v = -3e38f;
        }
        s[ni][j] = v;
      }

    float scl[4];
    #pragma unroll
    for (int j = 0; j < 4; j++) {
      float pm = fmaxf(fmaxf(s[0][j], s[1][j]), fmaxf(s[2][j], s[3][j]));
      #pragma unroll
      for (int m = 1; m < 16; m <<= 1) pm = fmaxf(pm, __shfl_xor(pm, m));
      const float mn = fmaxf(mrow[j], pm);
      scl[j] = __expf(mrow[j] - mn);
      mrow[j] = mn;
      float rs = 0.f;
      #pragma unroll
      for (int ni = 0; ni < 4; ni++) {
        const float p = __expf(s[ni][j] - mn);
        s[ni][j] = p;
        rs += p;
      }
      #pragma unroll
      for (int m = 1; m < 16; m <<= 1) rs += __shfl_xor(rs, m);
      lrow[j] = lrow[j] * scl[j] + rs;
    }
    #pragma unroll
    for (int ni = 0; ni < 8; ni++)
      #pragma unroll
      for (int j = 0; j < 4; j++) o[ni][j] *= scl[j];

    unsigned short* pw = pS[w];
    #pragma unroll
    for (int ni = 0; ni < 4; ni++)
      #pragma unroll
      for (int j = 0; j < 4; j++) {
        const int prow = (lane >> 4) * 4 + j;
        const int boff = (prow * 128 + (ni * 16 + (lane & 15)) * 2) ^ ((prow & 7) << 4);
        *(unsigned short*)((char*)pw + boff) = f2bf(s[ni][j]);
      }
    #pragma unroll
    for (int kk = 0; kk < 2; kk++) {
      const int pr = lane & 15;
      bf16x8 pa = *(const bf16x8*)((char*)pw + ((pr * 128 + kk * 64 + (lane >> 4) * 16) ^ ((pr & 7) << 4)));
      #pragma unroll
      for (int ni = 0; ni < 8; ni++) {
        const int rv = ni * 16 + (lane & 15);
        bf16x8 vb = *(const bf16x8*)(vSc + ((rv * 128 + kk * 64 + (lane >> 4) * 16) ^ ((rv & 7) << 4)));
        o[ni] = __builtin_amdgcn_mfma_f32_16x16x32_bf16(pa, vb, o[ni], 0, 0, 0);
      }
    }
    __syncthreads();
  }

  const size_t orow = ((size_t)b * T_ + q0 + w * 16 + (lane >> 4) * 4) * (H_ * HD_)
                      + h * HD_ + (lane & 15);
  #pragma unroll
  for (int ni = 0; ni < 8; ni++)
    #pragma unroll
    for (int j = 0; j < 4; j++)
      out[orow + (size_t)j * (H_ * HD_) + ni * 16] = f2bf(o[ni][j] / lrow[j]);
}

// ===========================================================================
extern "C" void kernel_launch(void* const* d_in, const int* in_sizes, int n_in,
                              void* d_out, int out_size, void* d_ws, size_t ws_size,
                              hipStream_t stream) {
  const float* hs   = (const float*)d_in[0];
  const float* ke   = (const float*)d_in[1];
  const float* ve   = (const float*)d_in[2];
  const float* cosT = (const float*)d_in[3];
  const float* sinT = (const float*)d_in[4];
  // d_in[5] = attention_mask: deterministic causal, applied analytically.
  const float* alog = (const float*)d_in[6];
  const float* Wq   = (const float*)d_in[7];
  const float* Wk   = (const float*)d_in[8];
  const float* Wv   = (const float*)d_in[9];
  const float* Wo   = (const float*)d_in[10];
  const float* qnw  = (const float*)d_in[11];
  const float* knw  = (const float*)d_in[12];
  const float* ln1  = (const float*)d_in[13];
  const float* ln2  = (const float*)d_in[14];
  const float* Wg   = (const float*)d_in[15];
  const float* Wu   = (const float*)d_in[16];
  const float* Wd   = (const float*)d_in[17];

  char* ws = (char*)d_ws;
  size_t off = 0;
  auto alloc = [&](size_t bytes) {
    void* p = ws + off;
    off += (bytes + 255) & ~(size_t)255;
    return p;
  };
  const int M = B_ * T_;  // 4096
  unsigned short* h     = (unsigned short*)alloc((size_t)M * D_ * 2);
  unsigned short* wt    = (unsigned short*)alloc((size_t)DFF_ * D_ * 2);
  unsigned short* qbuf  = (unsigned short*)alloc((size_t)M * 2048 * 2);
  unsigned short* kbuf  = (unsigned short*)alloc((size_t)M * 1024 * 2);
  unsigned short* vbuf  = (unsigned short*)alloc((size_t)M * 1024 * 2);
  unsigned short* qrope = (unsigned short*)alloc((size_t)B_ * H_ * T_ * HD_ * 2);
  unsigned short* kall  = (unsigned short*)alloc((size_t)B_ * HKV_ * TK_ * HD_ * 2);
  unsigned short* vallT = (unsigned short*)alloc((size_t)B_ * HKV_ * TK_ * HD_ * 2);
  float*          hidden= (float*)alloc((size_t)M * D_ * 4);
  unsigned short* g     = (unsigned short*)alloc((size_t)M * DFF_ * 2);

  // 1) input layernorm
  k_rmsnorm<<<M, 256, 0, stream>>>(hs, ln1, h);
  // 2) Q projection + head norm + RoPE
  k_wtrans<<<dim3(2048 / 32, 2048 / 32), 256, 0, stream>>>(Wq, wt, 2048, 2048);
  k_gemm<0><<<dim3(2048 / 128, M / 128), 256, 0, stream>>>(h, wt, qbuf, nullptr, nullptr, M, 2048, 2048);
  k_qknorm<1><<<dim3(T_, H_, B_), 128, 0, stream>>>(qbuf, qnw, cosT, sinT, qrope);
  // 3) K projection + head norm + RoPE + virtual K
  k_wtrans<<<dim3(1024 / 32, 2048 / 32), 256, 0, stream>>>(Wk, wt, 2048, 1024);
  k_gemm<0><<<dim3(1024 / 128, M / 128), 256, 0, stream>>>(h, wt, kbuf, nullptr, nullptr, M, 1024, 2048);
  k_qknorm<0><<<dim3(T_, HKV_, B_), 128, 0, stream>>>(kbuf, knw, cosT, sinT, kall);
  k_kvirt<<<(B_ * HKV_ * R_ * HD_) / 256, 256, 0, stream>>>(ke, alog, kall);
  // 4) V projection + transposed concat
  k_wtrans<<<dim3(1024 / 32, 2048 / 32), 256, 0, stream>>>(Wv, wt, 2048, 1024);
  k_gemm<0><<<dim3(1024 / 128, M / 128), 256, 0, stream>>>(h, wt, vbuf, nullptr, nullptr, M, 1024, 2048);
  k_vbuild<<<dim3(TK_ / 32, HD_ / 32, B_ * HKV_), 256, 0, stream>>>(vbuf, ve, alog, vallT);
  // 5) attention
  k_attn<<<dim3(T_ / 64, H_, B_), 256, 0, stream>>>(qrope, kall, vallT, qbuf);
  // 6) output projection + residual
  k_wtrans<<<dim3(2048 / 32, 2048 / 32), 256, 0, stream>>>(Wo, wt, 2048, 2048);
  k_gemm<1><<<dim3(2048 / 128, M / 128), 256, 0, stream>>>(qbuf, wt, hidden, hs, nullptr, M, 2048, 2048);
  // 7) post-attn layernorm
  k_rmsnorm<<<M, 256, 0, stream>>>(hidden, ln2, h);
  // 8) SwiGLU MLP + residual (silu*u fused into the Wu GEMM epilogue)
  k_wtrans<<<dim3(DFF_ / 32, 2048 / 32), 256, 0, stream>>>(Wg, wt, 2048, DFF_);
  k_gemm<0><<<dim3(DFF_ / 128, M / 128), 256, 0, stream>>>(h, wt, g, nullptr, nullptr, M, DFF_, 2048);
  k_wtrans<<<dim3(DFF_ / 32, 2048 / 32), 256, 0, stream>>>(Wu, wt, 2048, DFF_);
  k_gemm<2><<<dim3(DFF_ / 128, M / 128), 256, 0, stream>>>(h, wt, g, nullptr, g, M, DFF_, 2048);
  k_wtrans<<<dim3(2048 / 32, DFF_ / 32), 256, 0, stream>>>(Wd, wt, DFF_, 2048);
  k_gemm<1><<<dim3(2048 / 128, M / 128), 256, 0, stream>>>(g, wt, (float*)d_out, hidden, nullptr, M, 2048, DFF_);
}

// Round 3
// 962.270 us; speedup vs baseline: 1.2575x; 1.0342x over previous
//
#include <hip/hip_runtime.h>
#include <hip/hip_bf16.h>

// ===========================================================================
// Decoder layer: RMSNorm -> QKV(+head RMSNorm+RoPE) -> GQA attn with R=128
// virtual KV tokens -> Wo + residual -> RMSNorm -> SwiGLU MLP -> residual.
// Round 3: attention rewritten — 128-q-row blocks, K/V staged via
// global_load_lds (pre-swizzled global source), double-buffered LDS with one
// barrier per tile; vallT stored key-tiled for coalesced V staging.
// ===========================================================================

#define DEV __device__ __forceinline__

using f32x4  = __attribute__((ext_vector_type(4))) float;
using bf16x8 = __attribute__((ext_vector_type(8))) short;

constexpr int B_ = 2, T_ = 2048, D_ = 2048, H_ = 16, HKV_ = 8, HD_ = 128;
constexpr int R_ = 128, DFF_ = 6144, TK_ = R_ + T_;   // TK_=2176
constexpr int NT64_ = TK_ / 64;                       // 34 key-tiles
constexpr float EPS_ = 1e-6f;
constexpr float SCALING_ = 0.08838834764831845f;      // 128^-0.5

DEV float bf2f(unsigned short u) {
  unsigned int x = ((unsigned int)u) << 16;
  return __builtin_bit_cast(float, x);
}
DEV unsigned short f2bf(float f) {
  unsigned int x = __builtin_bit_cast(unsigned int, f);
  x += 0x7fffu + ((x >> 16) & 1u);   // RNE
  return (unsigned short)(x >> 16);
}

// async global -> LDS, 16B per lane. lds base wave-uniform; HW writes lane l
// at lds + l*16. global source address is per-lane.
DEV void gload_lds16(const void* g, void* l) {
  __builtin_amdgcn_global_load_lds((__attribute__((address_space(1))) void*)(g),
                                   (__attribute__((address_space(3))) void*)(l),
                                   16, 0, 0);
}

// ---------------------------------------------------------------------------
// RMSNorm (fp32 in, bf16 out). One block per row of D=2048, 256 thr x 8 elem.
// ---------------------------------------------------------------------------
__global__ __launch_bounds__(256) void k_rmsnorm(const float* __restrict__ x,
                                                 const float* __restrict__ w,
                                                 unsigned short* __restrict__ out) {
  const int row = blockIdx.x;
  const float* xr = x + (size_t)row * D_;
  const int t8 = threadIdx.x * 8;
  float4 a = *(const float4*)(xr + t8);
  float4 b = *(const float4*)(xr + t8 + 4);
  float ss = a.x*a.x + a.y*a.y + a.z*a.z + a.w*a.w
           + b.x*b.x + b.y*b.y + b.z*b.z + b.w*b.w;
  #pragma unroll
  for (int m = 1; m < 64; m <<= 1) ss += __shfl_xor(ss, m);
  __shared__ float red[4];
  if ((threadIdx.x & 63) == 0) red[threadIdx.x >> 6] = ss;
  __syncthreads();
  ss = red[0] + red[1] + red[2] + red[3];
  const float sc = rsqrtf(ss * (1.0f / D_) + EPS_);
  float4 wa = *(const float4*)(w + t8);
  float4 wb = *(const float4*)(w + t8 + 4);
  bf16x8 ov;
  ov[0] = (short)f2bf(a.x * sc * wa.x); ov[1] = (short)f2bf(a.y * sc * wa.y);
  ov[2] = (short)f2bf(a.z * sc * wa.z); ov[3] = (short)f2bf(a.w * sc * wa.w);
  ov[4] = (short)f2bf(b.x * sc * wb.x); ov[5] = (short)f2bf(b.y * sc * wb.y);
  ov[6] = (short)f2bf(b.z * sc * wb.z); ov[7] = (short)f2bf(b.w * sc * wb.w);
  *(bf16x8*)(out + (size_t)row * D_ + t8) = ov;
}

// ---------------------------------------------------------------------------
// Weight transpose+convert: W (K,N) fp32 row-major -> Wt (N,K) bf16 row-major.
// ---------------------------------------------------------------------------
__global__ __launch_bounds__(256) void k_wtrans(const float* __restrict__ W,
                                                unsigned short* __restrict__ Wt,
                                                int K, int N) {
  __shared__ float tile[32][33];
  const int n0 = blockIdx.x * 32, k0 = blockIdx.y * 32;
  {
    const int kl = threadIdx.x >> 3, nc = (threadIdx.x & 7) * 4;
    float4 f = *(const float4*)(W + (size_t)(k0 + kl) * N + n0 + nc);
    tile[kl][nc] = f.x; tile[kl][nc + 1] = f.y;
    tile[kl][nc + 2] = f.z; tile[kl][nc + 3] = f.w;
  }
  __syncthreads();
  const int nl = threadIdx.x >> 3, kc = (threadIdx.x & 7) * 4;
  ushort4 o;
  o.x = f2bf(tile[kc][nl]);     o.y = f2bf(tile[kc + 1][nl]);
  o.z = f2bf(tile[kc + 2][nl]); o.w = f2bf(tile[kc + 3][nl]);
  *(ushort4*)(Wt + (size_t)(n0 + nl) * K + k0 + kc) = o;
}

// ---------------------------------------------------------------------------
// GEMM: C(M,N) = A(M,K) @ Bt(N,K)^T, bf16 in, fp32 accum. 128x128 tile, BK=64,
// 4 waves (2x2), 4x4 16x16x32 frags. global_load_lds width-16 staging (m97).
// EPI=0: bf16 out. EPI=1: fp32 out = acc + resid. EPI=2: bf16 = silu(gmul)*acc.
// ---------------------------------------------------------------------------
template <int EPI>
__global__ __launch_bounds__(256) void k_gemm(const unsigned short* __restrict__ A,
                                              const unsigned short* __restrict__ Bt,
                                              void* __restrict__ Cp,
                                              const float* __restrict__ resid,
                                              const unsigned short* __restrict__ gmul,
                                              int M, int N, int K) {
  __shared__ __align__(16) unsigned short lA[128 * 64];
  __shared__ __align__(16) unsigned short lB[128 * 64];
  const int tid = threadIdx.x;
  const int lane = tid & 63;
  const int wave = tid >> 6;
  const int wm = wave >> 1, wn = wave & 1;

  // XCD-aware bijective swizzle (nwg % 8 == 0 for all our shapes)
  const int nbx = (int)gridDim.x;
  const int nwg = nbx * (int)gridDim.y;
  int bid = (int)blockIdx.y * nbx + (int)blockIdx.x;
  if ((nwg & 7) == 0) bid = (bid & 7) * (nwg >> 3) + (bid >> 3);
  const int row0 = (bid / nbx) * 128, col0 = (bid % nbx) * 128;

  // staging map: instr i, wave w, lane l -> LDS byte i*4096 + w*1024 + l*16
  //   => tile row r = i*32 + w*8 + (l>>3), col8 = l&7  (linear [128][64] bf16)
  const int srw = wave * 8 + (lane >> 3);
  const unsigned short* pa = A  + (size_t)(row0 + srw) * K + (lane & 7) * 8;
  const unsigned short* pb = Bt + (size_t)(col0 + srw) * K + (lane & 7) * 8;
  char* lAc = (char*)lA;
  char* lBc = (char*)lB;
  const int ldsw = wave * 1024;

  f32x4 zero = {0.f, 0.f, 0.f, 0.f};
  f32x4 acc[4][4];
  #pragma unroll
  for (int i = 0; i < 4; i++)
    #pragma unroll
    for (int j = 0; j < 4; j++) acc[i][j] = zero;

  for (int k0 = 0; k0 < K; k0 += 64) {
    #pragma unroll
    for (int i = 0; i < 4; i++) {
      gload_lds16(pa + (size_t)i * 32 * K, lAc + ldsw + i * 4096);
      gload_lds16(pb + (size_t)i * 32 * K, lBc + ldsw + i * 4096);
    }
    __syncthreads();   // compiler drains vmcnt(0) before s_barrier
    #pragma unroll
    for (int kc = 0; kc < 2; ++kc) {
      bf16x8 af[4], bfr[4];
      #pragma unroll
      for (int i = 0; i < 4; i++) {
        const int ra = wm * 64 + i * 16 + (lane & 15);
        af[i]  = *(const bf16x8*)(lAc + ra * 128 + kc * 64 + (lane >> 4) * 16);
        const int rb = wn * 64 + i * 16 + (lane & 15);
        bfr[i] = *(const bf16x8*)(lBc + rb * 128 + kc * 64 + (lane >> 4) * 16);
      }
      #pragma unroll
      for (int mi = 0; mi < 4; mi++)
        #pragma unroll
        for (int ni = 0; ni < 4; ni++)
          acc[mi][ni] = __builtin_amdgcn_mfma_f32_16x16x32_bf16(af[mi], bfr[ni], acc[mi][ni], 0, 0, 0);
    }
    __syncthreads();
    pa += 64;
    pb += 64;
  }

  const int crow = row0 + wm * 64 + ((lane >> 4) * 4);
  const int ccol = col0 + wn * 64 + (lane & 15);
  #pragma unroll
  for (int mi = 0; mi < 4; mi++)
    #pragma unroll
    for (int ni = 0; ni < 4; ni++) {
      const int r = crow + mi * 16;
      const int c = ccol + ni * 16;
      if constexpr (EPI == 0) {
        unsigned short* C = (unsigned short*)Cp;
        #pragma unroll
        for (int j = 0; j < 4; j++) C[(size_t)(r + j) * N + c] = f2bf(acc[mi][ni][j]);
      } else if constexpr (EPI == 1) {
        float* C = (float*)Cp;
        #pragma unroll
        for (int j = 0; j < 4; j++)
          C[(size_t)(r + j) * N + c] = acc[mi][ni][j] + resid[(size_t)(r + j) * N + c];
      } else {
        unsigned short* C = (unsigned short*)Cp;
        #pragma unroll
        for (int j = 0; j < 4; j++) {
          const float gx = bf2f(gmul[(size_t)(r + j) * N + c]);
          C[(size_t)(r + j) * N + c] = f2bf(gx / (1.f + __expf(-gx)) * acc[mi][ni][j]);
        }
      }
    }
}

// ---------------------------------------------------------------------------
// Per-head RMSNorm + RoPE. in: (B,T,NH,HD) bf16 GEMM output.
// ISQ=1 -> q_rope (B,H,T,HD); ISQ=0 -> k_all[(B,HKV,TK)] rows R..R+T-1.
// ---------------------------------------------------------------------------
template <int ISQ>
__global__ __launch_bounds__(128) void k_qknorm(const unsigned short* __restrict__ in,
                                                const float* __restrict__ nw,
                                                const float* __restrict__ cosT,
                                                const float* __restrict__ sinT,
                                                unsigned short* __restrict__ out) {
  const int t = blockIdx.x, hh = blockIdx.y, b = blockIdx.z;
  const int NH = ISQ ? H_ : HKV_;
  const int hd = threadIdx.x;
  float v = bf2f(in[(((size_t)b * T_ + t) * NH + hh) * HD_ + hd]);
  float ss = v * v;
  #pragma unroll
  for (int m = 1; m < 64; m <<= 1) ss += __shfl_xor(ss, m);
  __shared__ float red[2];
  __shared__ float buf[128];
  if ((hd & 63) == 0) red[hd >> 6] = ss;
  __syncthreads();
  ss = red[0] + red[1];
  const float nv = v * rsqrtf(ss * (1.0f / HD_) + EPS_) * nw[hd];
  buf[hd] = nv;
  __syncthreads();
  const float rot = hd < 64 ? -buf[hd + 64] : buf[hd - 64];
  const float o = nv * cosT[(size_t)t * HD_ + hd] + rot * sinT[(size_t)t * HD_ + hd];
  if (ISQ) out[(((size_t)b * H_ + hh) * T_ + t) * HD_ + hd] = f2bf(o);
  else     out[(((size_t)b * HKV_ + hh) * TK_ + R_ + t) * HD_ + hd] = f2bf(o);
}

// ---------------------------------------------------------------------------
// Virtual K rows: k_all[.., 0..R-1, ..] = k_extra * eff  (eff = 0.5*sigmoid(a))
// ---------------------------------------------------------------------------
__global__ __launch_bounds__(256) void k_kvirt(const float* __restrict__ ke,
                                               const float* __restrict__ alog,
                                               unsigned short* __restrict__ k_all) {
  const size_t i = (size_t)blockIdx.x * 256 + threadIdx.x;  // B*HKV*R*HD = 262144
  const float eff = 0.5f / (1.f + __expf(-alog[0]));
  const int hd = (int)(i & 127);
  const int r  = (int)((i >> 7) & 127);
  const int bk = (int)(i >> 14);
  k_all[((size_t)bk * TK_ + r) * HD_ + hd] = f2bf(ke[i] * eff);
}

// ---------------------------------------------------------------------------
// Build v_allT, key-tiled: (B,HKV, NT64, HD, 64key) bf16 from [v_extra*eff ; v]
// ---------------------------------------------------------------------------
__global__ __launch_bounds__(256) void k_vbuild(const unsigned short* __restrict__ vbuf,
                                                const float* __restrict__ ve,
                                                const float* __restrict__ alog,
                                                unsigned short* __restrict__ vT) {
  __shared__ float tile[32][33];
  const int kt = blockIdx.x, ht = blockIdx.y, bk = blockIdx.z;
  const int b = bk >> 3, kvh = bk & 7;
  const float eff = 0.5f / (1.f + __expf(-alog[0]));
  const int kl = threadIdx.x >> 3, hc = (threadIdx.x & 7) * 4;
  const int key = kt * 32 + kl, hd0 = ht * 32;
  if (key < R_) {
    float4 f = *(const float4*)(ve + (((size_t)(b * HKV_ + kvh) * R_ + key) * HD_ + hd0 + hc));
    tile[kl][hc] = f.x * eff; tile[kl][hc + 1] = f.y * eff;
    tile[kl][hc + 2] = f.z * eff; tile[kl][hc + 3] = f.w * eff;
  } else {
    const unsigned short* s = vbuf + (((size_t)(b * T_ + key - R_) * HKV_ + kvh) * HD_ + hd0 + hc);
    ushort4 u = *(const ushort4*)s;
    tile[kl][hc] = bf2f(u.x); tile[kl][hc + 1] = bf2f(u.y);
    tile[kl][hc + 2] = bf2f(u.z); tile[kl][hc + 3] = bf2f(u.w);
  }
  __syncthreads();
  const int hl = threadIdx.x >> 3, kc = (threadIdx.x & 7) * 4;
  ushort4 o;
  o.x = f2bf(tile[kc][hl]);     o.y = f2bf(tile[kc + 1][hl]);
  o.z = f2bf(tile[kc + 2][hl]); o.w = f2bf(tile[kc + 3][hl]);
  // key-tiled store: keys kt*32+kc.. stay within 64-tile (kt>>1), slot (kt&1)*32+kc
  *(ushort4*)(vT + ((size_t)bk * NT64_ + (kt >> 1)) * (HD_ * 64)
                  + (size_t)(hd0 + hl) * 64 + (kt & 1) * 32 + kc) = o;
}

// ---------------------------------------------------------------------------
// Flash attention. 256 thr (4 waves), 128 q-rows/block (32/wave), 64-key tiles.
// K/V double-buffered in LDS via global_load_lds with pre-swizzled global src;
// one barrier per tile (stage t+1 overlaps compute t).
// ---------------------------------------------------------------------------
__global__ __launch_bounds__(256, 2) void k_attn(const unsigned short* __restrict__ qr,
                                                 const unsigned short* __restrict__ k_all,
                                                 const unsigned short* __restrict__ vT,
                                                 unsigned short* __restrict__ out) {
  __shared__ __align__(16) unsigned short kT[2][64 * 128];   // [key][hd], swizzled
  __shared__ __align__(16) unsigned short vS[2][128 * 64];   // [hd][key], swizzled
  __shared__ __align__(16) unsigned short pS[4][32 * 64];    // per-wave P, swizzled
  const int tid = threadIdx.x, lane = tid & 63, w = tid >> 6;
  const int qb = blockIdx.x, h = blockIdx.y, b = blockIdx.z;
  const int kvh = h >> 1;   // G = 2
  const int q0 = qb * 128;

  // Q frags: 32 rows/wave = 2 row-frags of 16
  bf16x8 qf[2][4];
  #pragma unroll
  for (int fq = 0; fq < 2; fq++) {
    const unsigned short* qbase =
        qr + ((size_t)((b * H_ + h) * T_) + q0 + w * 32 + fq * 16 + (lane & 15)) * HD_ + (lane >> 4) * 8;
    #pragma unroll
    for (int kc = 0; kc < 4; kc++) qf[fq][kc] = *(const bf16x8*)(qbase + kc * 32);
  }

  f32x4 zero = {0.f, 0.f, 0.f, 0.f};
  f32x4 o[2][8];
  #pragma unroll
  for (int fq = 0; fq < 2; fq++)
    #pragma unroll
    for (int i = 0; i < 8; i++) o[fq][i] = zero;
  float mrow[2][4], lrow[2][4];
  #pragma unroll
  for (int fq = 0; fq < 2; fq++)
    #pragma unroll
    for (int j = 0; j < 4; j++) { mrow[fq][j] = -3e38f; lrow[fq][j] = 0.f; }

  // Per-lane pre-swizzled staging sources (rule #21: linear LDS dest +
  // inverse-swizzled source + swizzled read).
  // K: LDS byte L=i*4096+w*1024+l*16 -> row r=i*16+w*4+(l>>4), colb=(l&15)*16
  const int kr0 = w * 4 + (lane >> 4);
  const char* kSrc = (const char*)(k_all + (size_t)(b * HKV_ + kvh) * TK_ * HD_)
                     + (size_t)kr0 * 256 + (((lane & 15) * 16) ^ ((kr0 & 7) << 4));
  // V: row hv=i*32+w*8+(l>>3), colb=(l&7)*16 ; hv&7 = (l>>3)&7
  const char* vSrc = (const char*)(vT + (size_t)(b * HKV_ + kvh) * NT64_ * HD_ * 64)
                     + (size_t)(w * 8 + (lane >> 3)) * 128
                     + (((lane & 7) * 16) ^ (((lane >> 3) & 7) << 4));
  char* kL = (char*)kT;
  char* vL = (char*)vS;
  char* pw = (char*)pS[w];
  const int ldsw = w * 1024;

  const int ntiles = 2 * qb + 4;
  // prologue: stage tile 0 -> buf 0
  #pragma unroll
  for (int i = 0; i < 4; i++) {
    gload_lds16(kSrc + i * 4096, kL + ldsw + i * 4096);
    gload_lds16(vSrc + i * 4096, vL + ldsw + i * 4096);
  }
  int cur = 0;

  for (int it = 0; it < ntiles; ++it) {
    __syncthreads();   // drains vmcnt(0): buf[cur] staged; prev compute done
    if (it + 1 < ntiles) {
      const char* ks = kSrc + (size_t)(it + 1) * 16384;
      const char* vs = vSrc + (size_t)(it + 1) * 16384;
      char* kd = kL + ((cur ^ 1) * 16384 + ldsw);
      char* vd = vL + ((cur ^ 1) * 16384 + ldsw);
      #pragma unroll
      for (int i = 0; i < 4; i++) {
        gload_lds16(ks + i * 4096, kd + i * 4096);
        gload_lds16(vs + i * 4096, vd + i * 4096);
      }
    }
    const char* kTc = kL + cur * 16384;
    const char* vSc = vL + cur * 16384;

    // S = Q K^T : 32 rows x 64 keys per wave; K frags shared across row-frags
    f32x4 s[2][4];
    #pragma unroll
    for (int ni = 0; ni < 4; ni++) { s[0][ni] = zero; s[1][ni] = zero; }
    #pragma unroll
    for (int ni = 0; ni < 4; ni++) {
      const int rk = ni * 16 + (lane & 15);
      const int swz = (rk & 7) << 4;
      #pragma unroll
      for (int kc = 0; kc < 4; kc++) {
        bf16x8 kf = *(const bf16x8*)(kTc + ((rk * 256 + kc * 64 + (lane >> 4) * 16) ^ swz));
        s[0][ni] = __builtin_amdgcn_mfma_f32_16x16x32_bf16(qf[0][kc], kf, s[0][ni], 0, 0, 0);
        s[1][ni] = __builtin_amdgcn_mfma_f32_16x16x32_bf16(qf[1][kc], kf, s[1][ni], 0, 0, 0);
      }
    }

    const bool domask = (it >= ntiles - 2);
    #pragma unroll
    for (int fq = 0; fq < 2; fq++) {
      #pragma unroll
      for (int ni = 0; ni < 4; ni++)
        #pragma unroll
        for (int j = 0; j < 4; j++) {
          float v = s[fq][ni][j] * SCALING_;
          if (domask) {
            const int key = it * 64 + ni * 16 + (lane & 15);
            const int rl  = w * 32 + fq * 16 + (lane >> 4) * 4 + j;
            if (key > R_ + q0 + rl) v = -3e38f;
          }
          s[fq][ni][j] = v;
        }
      // online softmax (rows live in 16-lane groups)
      float scl[4];
      #pragma unroll
      for (int j = 0; j < 4; j++) {
        float pm = fmaxf(fmaxf(s[fq][0][j], s[fq][1][j]), fmaxf(s[fq][2][j], s[fq][3][j]));
        #pragma unroll
        for (int m = 1; m < 16; m <<= 1) pm = fmaxf(pm, __shfl_xor(pm, m));
        const float mn = fmaxf(mrow[fq][j], pm);
        scl[j] = __expf(mrow[fq][j] - mn);
        mrow[fq][j] = mn;
        float rs = 0.f;
        #pragma unroll
        for (int ni = 0; ni < 4; ni++) {
          const float p = __expf(s[fq][ni][j] - mn);
          s[fq][ni][j] = p;
          rs += p;
        }
        #pragma unroll
        for (int m = 1; m < 16; m <<= 1) rs += __shfl_xor(rs, m);
        lrow[fq][j] = lrow[fq][j] * scl[j] + rs;
      }
      #pragma unroll
      for (int ni = 0; ni < 8; ni++)
        #pragma unroll
        for (int j = 0; j < 4; j++) o[fq][ni][j] *= scl[j];
      // P -> pS rows fq*16.. (per-wave private region; same-wave ordering)
      #pragma unroll
      for (int ni = 0; ni < 4; ni++)
        #pragma unroll
        for (int j = 0; j < 4; j++) {
          const int pr = fq * 16 + (lane >> 4) * 4 + j;
          const int boff = (pr * 128 + (ni * 16 + (lane & 15)) * 2) ^ ((pr & 7) << 4);
          *(unsigned short*)(pw + boff) = f2bf(s[fq][ni][j]);
        }
    }

    // PV: V frags shared across both row-frags
    #pragma unroll
    for (int kk = 0; kk < 2; kk++) {
      bf16x8 pa[2];
      #pragma unroll
      for (int fq = 0; fq < 2; fq++) {
        const int pr = fq * 16 + (lane & 15);
        pa[fq] = *(const bf16x8*)(pw + ((pr * 128 + kk * 64 + (lane >> 4) * 16) ^ ((pr & 7) << 4)));
      }
      #pragma unroll
      for (int ni = 0; ni < 8; ni++) {
        const int rv = ni * 16 + (lane & 15);
        bf16x8 vb = *(const bf16x8*)(vSc + ((rv * 128 + kk * 64 + (lane >> 4) * 16) ^ ((rv & 7) << 4)));
        o[0][ni] = __builtin_amdgcn_mfma_f32_16x16x32_bf16(pa[0], vb, o[0][ni], 0, 0, 0);
        o[1][ni] = __builtin_amdgcn_mfma_f32_16x16x32_bf16(pa[1], vb, o[1][ni], 0, 0, 0);
      }
    }
    cur ^= 1;
  }

  // out (B,T,H*HD) bf16
  #pragma unroll
  for (int fq = 0; fq < 2; fq++) {
    const size_t orow = ((size_t)b * T_ + q0 + w * 32 + fq * 16 + (lane >> 4) * 4) * (H_ * HD_)
                        + h * HD_ + (lane & 15);
    #pragma unroll
    for (int ni = 0; ni < 8; ni++)
      #pragma unroll
      for (int j = 0; j < 4; j++)
        out[orow + (size_t)j * (H_ * HD_) + ni * 16] = f2bf(o[fq][ni][j] / lrow[fq][j]);
  }
}

// ===========================================================================
extern "C" void kernel_launch(void* const* d_in, const int* in_sizes, int n_in,
                              void* d_out, int out_size, void* d_ws, size_t ws_size,
                              hipStream_t stream) {
  const float* hs   = (const float*)d_in[0];
  const float* ke   = (const float*)d_in[1];
  const float* ve   = (const float*)d_in[2];
  const float* cosT = (const float*)d_in[3];
  const float* sinT = (const float*)d_in[4];
  // d_in[5] = attention_mask: deterministic causal, applied analytically.
  const float* alog = (const float*)d_in[6];
  const float* Wq   = (const float*)d_in[7];
  const float* Wk   = (const float*)d_in[8];
  const float* Wv   = (const float*)d_in[9];
  const float* Wo   = (const float*)d_in[10];
  const float* qnw  = (const float*)d_in[11];
  const float* knw  = (const float*)d_in[12];
  const float* ln1  = (const float*)d_in[13];
  const float* ln2  = (const float*)d_in[14];
  const float* Wg   = (const float*)d_in[15];
  const float* Wu   = (const float*)d_in[16];
  const float* Wd   = (const float*)d_in[17];

  char* ws = (char*)d_ws;
  size_t off = 0;
  auto alloc = [&](size_t bytes) {
    void* p = ws + off;
    off += (bytes + 255) & ~(size_t)255;
    return p;
  };
  const int M = B_ * T_;  // 4096
  unsigned short* h     = (unsigned short*)alloc((size_t)M * D_ * 2);
  unsigned short* wt    = (unsigned short*)alloc((size_t)DFF_ * D_ * 2);
  unsigned short* qbuf  = (unsigned short*)alloc((size_t)M * 2048 * 2);
  unsigned short* kbuf  = (unsigned short*)alloc((size_t)M * 1024 * 2);
  unsigned short* vbuf  = (unsigned short*)alloc((size_t)M * 1024 * 2);
  unsigned short* qrope = (unsigned short*)alloc((size_t)B_ * H_ * T_ * HD_ * 2);
  unsigned short* kall  = (unsigned short*)alloc((size_t)B_ * HKV_ * TK_ * HD_ * 2);
  unsigned short* vallT = (unsigned short*)alloc((size_t)B_ * HKV_ * (size_t)NT64_ * HD_ * 64 * 2);
  float*          hidden= (float*)alloc((size_t)M * D_ * 4);
  unsigned short* g     = (unsigned short*)alloc((size_t)M * DFF_ * 2);

  // 1) input layernorm
  k_rmsnorm<<<M, 256, 0, stream>>>(hs, ln1, h);
  // 2) Q projection + head norm + RoPE
  k_wtrans<<<dim3(2048 / 32, 2048 / 32), 256, 0, stream>>>(Wq, wt, 2048, 2048);
  k_gemm<0><<<dim3(2048 / 128, M / 128), 256, 0, stream>>>(h, wt, qbuf, nullptr, nullptr, M, 2048, 2048);
  k_qknorm<1><<<dim3(T_, H_, B_), 128, 0, stream>>>(qbuf, qnw, cosT, sinT, qrope);
  // 3) K projection + head norm + RoPE + virtual K
  k_wtrans<<<dim3(1024 / 32, 2048 / 32), 256, 0, stream>>>(Wk, wt, 2048, 1024);
  k_gemm<0><<<dim3(1024 / 128, M / 128), 256, 0, stream>>>(h, wt, kbuf, nullptr, nullptr, M, 1024, 2048);
  k_qknorm<0><<<dim3(T_, HKV_, B_), 128, 0, stream>>>(kbuf, knw, cosT, sinT, kall);
  k_kvirt<<<(B_ * HKV_ * R_ * HD_) / 256, 256, 0, stream>>>(ke, alog, kall);
  // 4) V projection + key-tiled transposed concat
  k_wtrans<<<dim3(1024 / 32, 2048 / 32), 256, 0, stream>>>(Wv, wt, 2048, 1024);
  k_gemm<0><<<dim3(1024 / 128, M / 128), 256, 0, stream>>>(h, wt, vbuf, nullptr, nullptr, M, 1024, 2048);
  k_vbuild<<<dim3(TK_ / 32, HD_ / 32, B_ * HKV_), 256, 0, stream>>>(vbuf, ve, alog, vallT);
  // 5) attention (128 q-rows per block)
  k_attn<<<dim3(T_ / 128, H_, B_), 256, 0, stream>>>(qrope, kall, vallT, qbuf);
  // 6) output projection + residual
  k_wtrans<<<dim3(2048 / 32, 2048 / 32), 256, 0, stream>>>(Wo, wt, 2048, 2048);
  k_gemm<1><<<dim3(2048 / 128, M / 128), 256, 0, stream>>>(qbuf, wt, hidden, hs, nullptr, M, 2048, 2048);
  // 7) post-attn layernorm
  k_rmsnorm<<<M, 256, 0, stream>>>(hidden, ln2, h);
  // 8) SwiGLU MLP + residual (silu*u fused into the Wu GEMM epilogue)
  k_wtrans<<<dim3(DFF_ / 32, 2048 / 32), 256, 0, stream>>>(Wg, wt, 2048, DFF_);
  k_gemm<0><<<dim3(DFF_ / 128, M / 128), 256, 0, stream>>>(h, wt, g, nullptr, nullptr, M, DFF_, 2048);
  k_wtrans<<<dim3(DFF_ / 32, 2048 / 32), 256, 0, stream>>>(Wu, wt, 2048, DFF_);
  k_gemm<2><<<dim3(DFF_ / 128, M / 128), 256, 0, stream>>>(h, wt, g, nullptr, g, M, DFF_, 2048);
  k_wtrans<<<dim3(2048 / 32, DFF_ / 32), 256, 0, stream>>>(Wd, wt, DFF_, 2048);
  k_gemm<1><<<dim3(2048 / 128, M / 128), 256, 0, stream>>>(g, wt, (float*)d_out, hidden, nullptr, M, 2048, DFF_);
}

// Round 4
// 876.478 us; speedup vs baseline: 1.3806x; 1.0979x over previous
//
#include <hip/hip_runtime.h>
#include <hip/hip_bf16.h>

// ===========================================================================
// Decoder layer: RMSNorm -> QKV(+head RMSNorm+RoPE) -> GQA attn with R=128
// virtual KV tokens -> Wo + residual -> RMSNorm -> SwiGLU MLP -> residual.
// Round 4: attention uses swapped QK^T (S^T = K·Q^T) so P stays in registers
// (no P LDS round-trip), V key-columns pre-permuted in k_vbuild to match the
// register k-order; LDS 64 KiB -> 2 blocks/CU. k_qknorm regridded.
// ===========================================================================

#define DEV __device__ __forceinline__

using f32x4  = __attribute__((ext_vector_type(4))) float;
using bf16x8 = __attribute__((ext_vector_type(8))) short;

constexpr int B_ = 2, T_ = 2048, D_ = 2048, H_ = 16, HKV_ = 8, HD_ = 128;
constexpr int R_ = 128, DFF_ = 6144, TK_ = R_ + T_;   // TK_=2176
constexpr int NT64_ = TK_ / 64;                       // 34 key-tiles
constexpr float EPS_ = 1e-6f;
constexpr float SCALING_ = 0.08838834764831845f;      // 128^-0.5

DEV float bf2f(unsigned short u) {
  unsigned int x = ((unsigned int)u) << 16;
  return __builtin_bit_cast(float, x);
}
DEV unsigned short f2bf(float f) {
  unsigned int x = __builtin_bit_cast(unsigned int, f);
  x += 0x7fffu + ((x >> 16) & 1u);   // RNE
  return (unsigned short)(x >> 16);
}

// async global -> LDS, 16B per lane. lds base wave-uniform; HW writes lane l
// at lds + l*16. global source address is per-lane.
DEV void gload_lds16(const void* g, void* l) {
  __builtin_amdgcn_global_load_lds((__attribute__((address_space(1))) void*)(g),
                                   (__attribute__((address_space(3))) void*)(l),
                                   16, 0, 0);
}

// ---------------------------------------------------------------------------
// RMSNorm (fp32 in, bf16 out). One block per row of D=2048, 256 thr x 8 elem.
// ---------------------------------------------------------------------------
__global__ __launch_bounds__(256) void k_rmsnorm(const float* __restrict__ x,
                                                 const float* __restrict__ w,
                                                 unsigned short* __restrict__ out) {
  const int row = blockIdx.x;
  const float* xr = x + (size_t)row * D_;
  const int t8 = threadIdx.x * 8;
  float4 a = *(const float4*)(xr + t8);
  float4 b = *(const float4*)(xr + t8 + 4);
  float ss = a.x*a.x + a.y*a.y + a.z*a.z + a.w*a.w
           + b.x*b.x + b.y*b.y + b.z*b.z + b.w*b.w;
  #pragma unroll
  for (int m = 1; m < 64; m <<= 1) ss += __shfl_xor(ss, m);
  __shared__ float red[4];
  if ((threadIdx.x & 63) == 0) red[threadIdx.x >> 6] = ss;
  __syncthreads();
  ss = red[0] + red[1] + red[2] + red[3];
  const float sc = rsqrtf(ss * (1.0f / D_) + EPS_);
  float4 wa = *(const float4*)(w + t8);
  float4 wb = *(const float4*)(w + t8 + 4);
  bf16x8 ov;
  ov[0] = (short)f2bf(a.x * sc * wa.x); ov[1] = (short)f2bf(a.y * sc * wa.y);
  ov[2] = (short)f2bf(a.z * sc * wa.z); ov[3] = (short)f2bf(a.w * sc * wa.w);
  ov[4] = (short)f2bf(b.x * sc * wb.x); ov[5] = (short)f2bf(b.y * sc * wb.y);
  ov[6] = (short)f2bf(b.z * sc * wb.z); ov[7] = (short)f2bf(b.w * sc * wb.w);
  *(bf16x8*)(out + (size_t)row * D_ + t8) = ov;
}

// ---------------------------------------------------------------------------
// Weight transpose+convert: W (K,N) fp32 row-major -> Wt (N,K) bf16 row-major.
// ---------------------------------------------------------------------------
__global__ __launch_bounds__(256) void k_wtrans(const float* __restrict__ W,
                                                unsigned short* __restrict__ Wt,
                                                int K, int N) {
  __shared__ float tile[32][33];
  const int n0 = blockIdx.x * 32, k0 = blockIdx.y * 32;
  {
    const int kl = threadIdx.x >> 3, nc = (threadIdx.x & 7) * 4;
    float4 f = *(const float4*)(W + (size_t)(k0 + kl) * N + n0 + nc);
    tile[kl][nc] = f.x; tile[kl][nc + 1] = f.y;
    tile[kl][nc + 2] = f.z; tile[kl][nc + 3] = f.w;
  }
  __syncthreads();
  const int nl = threadIdx.x >> 3, kc = (threadIdx.x & 7) * 4;
  ushort4 o;
  o.x = f2bf(tile[kc][nl]);     o.y = f2bf(tile[kc + 1][nl]);
  o.z = f2bf(tile[kc + 2][nl]); o.w = f2bf(tile[kc + 3][nl]);
  *(ushort4*)(Wt + (size_t)(n0 + nl) * K + k0 + kc) = o;
}

// ---------------------------------------------------------------------------
// GEMM: C(M,N) = A(M,K) @ Bt(N,K)^T, bf16 in, fp32 accum. 128x128 tile, BK=64,
// 4 waves (2x2), 4x4 16x16x32 frags. global_load_lds width-16 staging (m97).
// EPI=0: bf16 out. EPI=1: fp32 out = acc + resid. EPI=2: bf16 = silu(gmul)*acc.
// ---------------------------------------------------------------------------
template <int EPI>
__global__ __launch_bounds__(256) void k_gemm(const unsigned short* __restrict__ A,
                                              const unsigned short* __restrict__ Bt,
                                              void* __restrict__ Cp,
                                              const float* __restrict__ resid,
                                              const unsigned short* __restrict__ gmul,
                                              int M, int N, int K) {
  __shared__ __align__(16) unsigned short lA[128 * 64];
  __shared__ __align__(16) unsigned short lB[128 * 64];
  const int tid = threadIdx.x;
  const int lane = tid & 63;
  const int wave = tid >> 6;
  const int wm = wave >> 1, wn = wave & 1;

  // XCD-aware bijective swizzle (nwg % 8 == 0 for all our shapes)
  const int nbx = (int)gridDim.x;
  const int nwg = nbx * (int)gridDim.y;
  int bid = (int)blockIdx.y * nbx + (int)blockIdx.x;
  if ((nwg & 7) == 0) bid = (bid & 7) * (nwg >> 3) + (bid >> 3);
  const int row0 = (bid / nbx) * 128, col0 = (bid % nbx) * 128;

  // staging map: instr i, wave w, lane l -> LDS byte i*4096 + w*1024 + l*16
  //   => tile row r = i*32 + w*8 + (l>>3), col8 = l&7  (linear [128][64] bf16)
  const int srw = wave * 8 + (lane >> 3);
  const unsigned short* pa = A  + (size_t)(row0 + srw) * K + (lane & 7) * 8;
  const unsigned short* pb = Bt + (size_t)(col0 + srw) * K + (lane & 7) * 8;
  char* lAc = (char*)lA;
  char* lBc = (char*)lB;
  const int ldsw = wave * 1024;

  f32x4 zero = {0.f, 0.f, 0.f, 0.f};
  f32x4 acc[4][4];
  #pragma unroll
  for (int i = 0; i < 4; i++)
    #pragma unroll
    for (int j = 0; j < 4; j++) acc[i][j] = zero;

  for (int k0 = 0; k0 < K; k0 += 64) {
    #pragma unroll
    for (int i = 0; i < 4; i++) {
      gload_lds16(pa + (size_t)i * 32 * K, lAc + ldsw + i * 4096);
      gload_lds16(pb + (size_t)i * 32 * K, lBc + ldsw + i * 4096);
    }
    __syncthreads();   // compiler drains vmcnt(0) before s_barrier
    #pragma unroll
    for (int kc = 0; kc < 2; ++kc) {
      bf16x8 af[4], bfr[4];
      #pragma unroll
      for (int i = 0; i < 4; i++) {
        const int ra = wm * 64 + i * 16 + (lane & 15);
        af[i]  = *(const bf16x8*)(lAc + ra * 128 + kc * 64 + (lane >> 4) * 16);
        const int rb = wn * 64 + i * 16 + (lane & 15);
        bfr[i] = *(const bf16x8*)(lBc + rb * 128 + kc * 64 + (lane >> 4) * 16);
      }
      #pragma unroll
      for (int mi = 0; mi < 4; mi++)
        #pragma unroll
        for (int ni = 0; ni < 4; ni++)
          acc[mi][ni] = __builtin_amdgcn_mfma_f32_16x16x32_bf16(af[mi], bfr[ni], acc[mi][ni], 0, 0, 0);
    }
    __syncthreads();
    pa += 64;
    pb += 64;
  }

  const int crow = row0 + wm * 64 + ((lane >> 4) * 4);
  const int ccol = col0 + wn * 64 + (lane & 15);
  #pragma unroll
  for (int mi = 0; mi < 4; mi++)
    #pragma unroll
    for (int ni = 0; ni < 4; ni++) {
      const int r = crow + mi * 16;
      const int c = ccol + ni * 16;
      if constexpr (EPI == 0) {
        unsigned short* C = (unsigned short*)Cp;
        #pragma unroll
        for (int j = 0; j < 4; j++) C[(size_t)(r + j) * N + c] = f2bf(acc[mi][ni][j]);
      } else if constexpr (EPI == 1) {
        float* C = (float*)Cp;
        #pragma unroll
        for (int j = 0; j < 4; j++)
          C[(size_t)(r + j) * N + c] = acc[mi][ni][j] + resid[(size_t)(r + j) * N + c];
      } else {
        unsigned short* C = (unsigned short*)Cp;
        #pragma unroll
        for (int j = 0; j < 4; j++) {
          const float gx = bf2f(gmul[(size_t)(r + j) * N + c]);
          C[(size_t)(r + j) * N + c] = f2bf(gx / (1.f + __expf(-gx)) * acc[mi][ni][j]);
        }
      }
    }
}

// ---------------------------------------------------------------------------
// Per-head RMSNorm + RoPE. in: (B,T,NH,HD) bf16. 16 rows per 256-thr block;
// 16 lanes per row (8 elems/lane); RoPE partner via shfl_xor 8.
// ISQ=1 -> q_rope (B,H,T,HD); ISQ=0 -> k_all[(B,HKV,TK)] rows R..R+T-1.
// ---------------------------------------------------------------------------
template <int ISQ>
__global__ __launch_bounds__(256) void k_qknorm(const unsigned short* __restrict__ in,
                                                const float* __restrict__ nw,
                                                const float* __restrict__ cosT,
                                                const float* __restrict__ sinT,
                                                unsigned short* __restrict__ out) {
  const int NH = ISQ ? H_ : HKV_;
  const int r = blockIdx.x * 16 + (threadIdx.x >> 4);
  const int l16 = threadIdx.x & 15;
  const int hd0 = l16 * 8;
  const int b = r / (T_ * NH), rem = r % (T_ * NH);
  const int t = rem / NH, hh = rem % NH;
  bf16x8 v = *(const bf16x8*)(in + (size_t)r * HD_ + hd0);
  float f[8];
  float ss = 0.f;
  #pragma unroll
  for (int j = 0; j < 8; j++) { f[j] = bf2f((unsigned short)v[j]); ss += f[j] * f[j]; }
  #pragma unroll
  for (int m = 1; m < 16; m <<= 1) ss += __shfl_xor(ss, m);
  const float sc = rsqrtf(ss * (1.0f / HD_) + EPS_);
  float4 wa = *(const float4*)(nw + hd0);
  float4 wb = *(const float4*)(nw + hd0 + 4);
  float nv[8];
  nv[0] = f[0] * sc * wa.x; nv[1] = f[1] * sc * wa.y;
  nv[2] = f[2] * sc * wa.z; nv[3] = f[3] * sc * wa.w;
  nv[4] = f[4] * sc * wb.x; nv[5] = f[5] * sc * wb.y;
  nv[6] = f[6] * sc * wb.z; nv[7] = f[7] * sc * wb.w;
  const float sgn = (hd0 < 64) ? -1.f : 1.f;
  float rot[8];
  #pragma unroll
  for (int j = 0; j < 8; j++) rot[j] = sgn * __shfl_xor(nv[j], 8);
  const float* cr = cosT + (size_t)t * HD_ + hd0;
  const float* sr = sinT + (size_t)t * HD_ + hd0;
  float4 ca = *(const float4*)cr, cb = *(const float4*)(cr + 4);
  float4 sa = *(const float4*)sr, sb = *(const float4*)(sr + 4);
  const float cv[8] = {ca.x, ca.y, ca.z, ca.w, cb.x, cb.y, cb.z, cb.w};
  const float sv[8] = {sa.x, sa.y, sa.z, sa.w, sb.x, sb.y, sb.z, sb.w};
  bf16x8 ov;
  #pragma unroll
  for (int j = 0; j < 8; j++) ov[j] = (short)f2bf(nv[j] * cv[j] + rot[j] * sv[j]);
  if (ISQ) *(bf16x8*)(out + (((size_t)b * H_ + hh) * T_ + t) * HD_ + hd0) = ov;
  else     *(bf16x8*)(out + (((size_t)b * HKV_ + hh) * TK_ + R_ + t) * HD_ + hd0) = ov;
}

// ---------------------------------------------------------------------------
// Virtual K rows: k_all[.., 0..R-1, ..] = k_extra * eff  (eff = 0.5*sigmoid(a))
// ---------------------------------------------------------------------------
__global__ __launch_bounds__(256) void k_kvirt(const float* __restrict__ ke,
                                               const float* __restrict__ alog,
                                               unsigned short* __restrict__ k_all) {
  const size_t i = (size_t)blockIdx.x * 256 + threadIdx.x;  // B*HKV*R*HD = 262144
  const float eff = 0.5f / (1.f + __expf(-alog[0]));
  const int hd = (int)(i & 127);
  const int r  = (int)((i >> 7) & 127);
  const int bk = (int)(i >> 14);
  k_all[((size_t)bk * TK_ + r) * HD_ + hd] = f2bf(ke[i] * eff);
}

// ---------------------------------------------------------------------------
// Build v_allT, key-tiled: (B,HKV, NT64, HD, 64key) bf16 from [v_extra*eff ; v].
// Key columns inside each 64-tile are PERMUTED to the PV register k-order:
// pos p = (n16>>1)*32 + g4*8 + (n16&1)*4 + j  for key = n16*16 + g4*4 + j.
// ---------------------------------------------------------------------------
__global__ __launch_bounds__(256) void k_vbuild(const unsigned short* __restrict__ vbuf,
                                                const float* __restrict__ ve,
                                                const float* __restrict__ alog,
                                                unsigned short* __restrict__ vT) {
  __shared__ float tile[32][33];
  const int kt = blockIdx.x, ht = blockIdx.y, bk = blockIdx.z;
  const int b = bk >> 3, kvh = bk & 7;
  const float eff = 0.5f / (1.f + __expf(-alog[0]));
  const int kl = threadIdx.x >> 3, hc = (threadIdx.x & 7) * 4;
  const int key = kt * 32 + kl, hd0 = ht * 32;
  if (key < R_) {
    float4 f = *(const float4*)(ve + (((size_t)(b * HKV_ + kvh) * R_ + key) * HD_ + hd0 + hc));
    tile[kl][hc] = f.x * eff; tile[kl][hc + 1] = f.y * eff;
    tile[kl][hc + 2] = f.z * eff; tile[kl][hc + 3] = f.w * eff;
  } else {
    const unsigned short* s = vbuf + (((size_t)(b * T_ + key - R_) * HKV_ + kvh) * HD_ + hd0 + hc);
    ushort4 u = *(const ushort4*)s;
    tile[kl][hc] = bf2f(u.x); tile[kl][hc + 1] = bf2f(u.y);
    tile[kl][hc + 2] = bf2f(u.z); tile[kl][hc + 3] = bf2f(u.w);
  }
  __syncthreads();
  const int hl = threadIdx.x >> 3, kc = (threadIdx.x & 7) * 4;
  ushort4 o;
  o.x = f2bf(tile[kc][hl]);     o.y = f2bf(tile[kc + 1][hl]);
  o.z = f2bf(tile[kc + 2][hl]); o.w = f2bf(tile[kc + 3][hl]);
  // column within the 64-key tile, then permute to PV k-order
  const int c0 = (kt & 1) * 32 + kc;
  const int p0 = ((c0 >> 5) << 5) | (((c0 >> 2) & 3) << 3) | (((c0 >> 4) & 1) << 2);
  *(ushort4*)(vT + ((size_t)bk * NT64_ + (kt >> 1)) * (HD_ * 64)
                  + (size_t)(hd0 + hl) * 64 + p0) = o;
}

// ---------------------------------------------------------------------------
// Flash attention. 256 thr (4 waves), 128 q-rows/block (32/wave), 64-key tiles.
// Swapped QK^T: S^T = mfma(K, Q) -> lane owns q-row (lane&15), keys in regs.
// P feeds PV straight from registers (V key-cols pre-permuted in k_vbuild).
// K/V double-buffered via global_load_lds, one barrier per tile. LDS 64 KiB.
// ---------------------------------------------------------------------------
__global__ __launch_bounds__(256, 2) void k_attn(const unsigned short* __restrict__ qr,
                                                 const unsigned short* __restrict__ k_all,
                                                 const unsigned short* __restrict__ vT,
                                                 unsigned short* __restrict__ out) {
  __shared__ __align__(16) unsigned short kT[2][64 * 128];   // [key][hd], swizzled
  __shared__ __align__(16) unsigned short vS[2][128 * 64];   // [hd][key-perm], swizzled
  const int tid = threadIdx.x, lane = tid & 63, w = tid >> 6;
  const int qb = (int)gridDim.x - 1 - (int)blockIdx.x;   // heavy blocks first
  const int h = blockIdx.y, b = blockIdx.z;
  const int kvh = h >> 1;   // G = 2
  const int q0 = qb * 128;

  // Q frags (B-operand): lane 16h+c -> row c of fq-group, k-elems h*8..+7
  bf16x8 qf[2][4];
  #pragma unroll
  for (int fq = 0; fq < 2; fq++) {
    const unsigned short* qbase =
        qr + ((size_t)((b * H_ + h) * T_) + q0 + w * 32 + fq * 16 + (lane & 15)) * HD_ + (lane >> 4) * 8;
    #pragma unroll
    for (int kc = 0; kc < 4; kc++) qf[fq][kc] = *(const bf16x8*)(qbase + kc * 32);
  }

  f32x4 zero = {0.f, 0.f, 0.f, 0.f};
  f32x4 o[2][8];
  #pragma unroll
  for (int fq = 0; fq < 2; fq++)
    #pragma unroll
    for (int i = 0; i < 8; i++) o[fq][i] = zero;
  float mrow[2] = {-3e38f, -3e38f}, lrow[2] = {0.f, 0.f};

  // staging sources (pre-swizzled global, rule #21) — unchanged from round 3
  const int kr0 = w * 4 + (lane >> 4);
  const char* kSrc = (const char*)(k_all + (size_t)(b * HKV_ + kvh) * TK_ * HD_)
                     + (size_t)kr0 * 256 + (((lane & 15) * 16) ^ ((kr0 & 7) << 4));
  const char* vSrc = (const char*)(vT + (size_t)(b * HKV_ + kvh) * NT64_ * HD_ * 64)
                     + (size_t)(w * 8 + (lane >> 3)) * 128
                     + (((lane & 7) * 16) ^ (((lane >> 3) & 7) << 4));
  char* kL = (char*)kT;
  char* vL = (char*)vS;
  const int ldsw = w * 1024;

  const int ntiles = 2 * qb + 4;
  #pragma unroll
  for (int i = 0; i < 4; i++) {
    gload_lds16(kSrc + i * 4096, kL + ldsw + i * 4096);
    gload_lds16(vSrc + i * 4096, vL + ldsw + i * 4096);
  }
  int cur = 0;

  for (int it = 0; it < ntiles; ++it) {
    __syncthreads();   // drains vmcnt(0): buf[cur] staged; prev compute done
    if (it + 1 < ntiles) {
      const char* ks = kSrc + (size_t)(it + 1) * 16384;
      const char* vs = vSrc + (size_t)(it + 1) * 16384;
      char* kd = kL + ((cur ^ 1) * 16384 + ldsw);
      char* vd = vL + ((cur ^ 1) * 16384 + ldsw);
      #pragma unroll
      for (int i = 0; i < 4; i++) {
        gload_lds16(ks + i * 4096, kd + i * 4096);
        gload_lds16(vs + i * 4096, vd + i * 4096);
      }
    }
    const char* kTc = kL + cur * 16384;
    const char* vSc = vL + cur * 16384;

    // S^T = K·Q^T : C col = q (lane&15), row = key (lane>>4)*4+j, frag ni=key16-group
    f32x4 s[2][4];
    #pragma unroll
    for (int ni = 0; ni < 4; ni++) { s[0][ni] = zero; s[1][ni] = zero; }
    #pragma unroll
    for (int ni = 0; ni < 4; ni++) {
      const int rk = ni * 16 + (lane & 15);
      const int swz = (rk & 7) << 4;
      #pragma unroll
      for (int kc = 0; kc < 4; kc++) {
        bf16x8 kf = *(const bf16x8*)(kTc + ((rk * 256 + kc * 64 + (lane >> 4) * 16) ^ swz));
        s[0][ni] = __builtin_amdgcn_mfma_f32_16x16x32_bf16(kf, qf[0][kc], s[0][ni], 0, 0, 0);
        s[1][ni] = __builtin_amdgcn_mfma_f32_16x16x32_bf16(kf, qf[1][kc], s[1][ni], 0, 0, 0);
      }
    }

    const bool domask = (it >= ntiles - 2);
    bf16x8 pa[2][2];
    #pragma unroll
    for (int fq = 0; fq < 2; fq++) {
      const int q = q0 + w * 32 + fq * 16 + (lane & 15);
      #pragma unroll
      for (int ni = 0; ni < 4; ni++)
        #pragma unroll
        for (int j = 0; j < 4; j++) {
          float v = s[fq][ni][j] * SCALING_;
          if (domask) {
            const int key = it * 64 + ni * 16 + (lane >> 4) * 4 + j;
            if (key > R_ + q) v = -3e38f;
          }
          s[fq][ni][j] = v;
        }
      // row-max over 16 own values + lanes l^16, l^32 (same q-row)
      float pm = -3e38f;
      #pragma unroll
      for (int ni = 0; ni < 4; ni++)
        #pragma unroll
        for (int j = 0; j < 4; j++) pm = fmaxf(pm, s[fq][ni][j]);
      pm = fmaxf(pm, __shfl_xor(pm, 16));
      pm = fmaxf(pm, __shfl_xor(pm, 32));
      const float mn = fmaxf(mrow[fq], pm);
      const float scl = __expf(mrow[fq] - mn);
      mrow[fq] = mn;
      float rs = 0.f;
      #pragma unroll
      for (int ni = 0; ni < 4; ni++)
        #pragma unroll
        for (int j = 0; j < 4; j++) {
          const float p = __expf(s[fq][ni][j] - mn);
          s[fq][ni][j] = p;
          rs += p;
        }
      rs += __shfl_xor(rs, 16);
      rs += __shfl_xor(rs, 32);
      lrow[fq] = lrow[fq] * scl + rs;
      // pack P a-frags: k-order m=h*8+ni2*4+j <-> key (2kc+ni2)*16+h*4+j
      #pragma unroll
      for (int kc2 = 0; kc2 < 2; kc2++) {
        bf16x8 t;
        #pragma unroll
        for (int j = 0; j < 4; j++) {
          t[j]     = (short)f2bf(s[fq][2 * kc2][j]);
          t[4 + j] = (short)f2bf(s[fq][2 * kc2 + 1][j]);
        }
        pa[fq][kc2] = t;
      }
      // rescale o: o rows are (lane>>4)*4+j -> fetch scl from owning lane
      #pragma unroll
      for (int j = 0; j < 4; j++) {
        const float sj = __shfl(scl, (lane & 48) | (((lane >> 4) << 2) + j));
        #pragma unroll
        for (int ni = 0; ni < 8; ni++) o[fq][ni][j] *= sj;
      }
    }

    // PV: o[q, hd] += P[q, k] V[k, hd]; V frags shared across both fq
    #pragma unroll
    for (int kc2 = 0; kc2 < 2; kc2++) {
      #pragma unroll
      for (int ni = 0; ni < 8; ni++) {
        const int rv = ni * 16 + (lane & 15);
        bf16x8 vb = *(const bf16x8*)(vSc + ((rv * 128 + kc2 * 64 + (lane >> 4) * 16) ^ ((rv & 7) << 4)));
        o[0][ni] = __builtin_amdgcn_mfma_f32_16x16x32_bf16(pa[0][kc2], vb, o[0][ni], 0, 0, 0);
        o[1][ni] = __builtin_amdgcn_mfma_f32_16x16x32_bf16(pa[1][kc2], vb, o[1][ni], 0, 0, 0);
      }
    }
    cur ^= 1;
  }

  // out (B,T,H*HD) bf16; lrow owned by lane (q=lane&15) -> broadcast per row
  #pragma unroll
  for (int fq = 0; fq < 2; fq++) {
    float linv[4];
    #pragma unroll
    for (int j = 0; j < 4; j++)
      linv[j] = 1.f / __shfl(lrow[fq], (lane & 48) | (((lane >> 4) << 2) + j));
    const size_t orow = ((size_t)b * T_ + q0 + w * 32 + fq * 16 + (lane >> 4) * 4) * (H_ * HD_)
                        + h * HD_ + (lane & 15);
    #pragma unroll
    for (int ni = 0; ni < 8; ni++)
      #pragma unroll
      for (int j = 0; j < 4; j++)
        out[orow + (size_t)j * (H_ * HD_) + ni * 16] = f2bf(o[fq][ni][j] * linv[j]);
  }
}

// ===========================================================================
extern "C" void kernel_launch(void* const* d_in, const int* in_sizes, int n_in,
                              void* d_out, int out_size, void* d_ws, size_t ws_size,
                              hipStream_t stream) {
  const float* hs   = (const float*)d_in[0];
  const float* ke   = (const float*)d_in[1];
  const float* ve   = (const float*)d_in[2];
  const float* cosT = (const float*)d_in[3];
  const float* sinT = (const float*)d_in[4];
  // d_in[5] = attention_mask: deterministic causal, applied analytically.
  const float* alog = (const float*)d_in[6];
  const float* Wq   = (const float*)d_in[7];
  const float* Wk   = (const float*)d_in[8];
  const float* Wv   = (const float*)d_in[9];
  const float* Wo   = (const float*)d_in[10];
  const float* qnw  = (const float*)d_in[11];
  const float* knw  = (const float*)d_in[12];
  const float* ln1  = (const float*)d_in[13];
  const float* ln2  = (const float*)d_in[14];
  const float* Wg   = (const float*)d_in[15];
  const float* Wu   = (const float*)d_in[16];
  const float* Wd   = (const float*)d_in[17];

  char* ws = (char*)d_ws;
  size_t off = 0;
  auto alloc = [&](size_t bytes) {
    void* p = ws + off;
    off += (bytes + 255) & ~(size_t)255;
    return p;
  };
  const int M = B_ * T_;  // 4096
  unsigned short* h     = (unsigned short*)alloc((size_t)M * D_ * 2);
  unsigned short* wt    = (unsigned short*)alloc((size_t)DFF_ * D_ * 2);
  unsigned short* qbuf  = (unsigned short*)alloc((size_t)M * 2048 * 2);
  unsigned short* kbuf  = (unsigned short*)alloc((size_t)M * 1024 * 2);
  unsigned short* vbuf  = (unsigned short*)alloc((size_t)M * 1024 * 2);
  unsigned short* qrope = (unsigned short*)alloc((size_t)B_ * H_ * T_ * HD_ * 2);
  unsigned short* kall  = (unsigned short*)alloc((size_t)B_ * HKV_ * TK_ * HD_ * 2);
  unsigned short* vallT = (unsigned short*)alloc((size_t)B_ * HKV_ * (size_t)NT64_ * HD_ * 64 * 2);
  float*          hidden= (float*)alloc((size_t)M * D_ * 4);
  unsigned short* g     = (unsigned short*)alloc((size_t)M * DFF_ * 2);

  // 1) input layernorm
  k_rmsnorm<<<M, 256, 0, stream>>>(hs, ln1, h);
  // 2) Q projection + head norm + RoPE
  k_wtrans<<<dim3(2048 / 32, 2048 / 32), 256, 0, stream>>>(Wq, wt, 2048, 2048);
  k_gemm<0><<<dim3(2048 / 128, M / 128), 256, 0, stream>>>(h, wt, qbuf, nullptr, nullptr, M, 2048, 2048);
  k_qknorm<1><<<(B_ * T_ * H_) / 16, 256, 0, stream>>>(qbuf, qnw, cosT, sinT, qrope);
  // 3) K projection + head norm + RoPE + virtual K
  k_wtrans<<<dim3(1024 / 32, 2048 / 32), 256, 0, stream>>>(Wk, wt, 2048, 1024);
  k_gemm<0><<<dim3(1024 / 128, M / 128), 256, 0, stream>>>(h, wt, kbuf, nullptr, nullptr, M, 1024, 2048);
  k_qknorm<0><<<(B_ * T_ * HKV_) / 16, 256, 0, stream>>>(kbuf, knw, cosT, sinT, kall);
  k_kvirt<<<(B_ * HKV_ * R_ * HD_) / 256, 256, 0, stream>>>(ke, alog, kall);
  // 4) V projection + key-tiled (k-order-permuted) transposed concat
  k_wtrans<<<dim3(1024 / 32, 2048 / 32), 256, 0, stream>>>(Wv, wt, 2048, 1024);
  k_gemm<0><<<dim3(1024 / 128, M / 128), 256, 0, stream>>>(h, wt, vbuf, nullptr, nullptr, M, 1024, 2048);
  k_vbuild<<<dim3(TK_ / 32, HD_ / 32, B_ * HKV_), 256, 0, stream>>>(vbuf, ve, alog, vallT);
  // 5) attention (128 q-rows per block)
  k_attn<<<dim3(T_ / 128, H_, B_), 256, 0, stream>>>(qrope, kall, vallT, qbuf);
  // 6) output projection + residual
  k_wtrans<<<dim3(2048 / 32, 2048 / 32), 256, 0, stream>>>(Wo, wt, 2048, 2048);
  k_gemm<1><<<dim3(2048 / 128, M / 128), 256, 0, stream>>>(qbuf, wt, hidden, hs, nullptr, M, 2048, 2048);
  // 7) post-attn layernorm
  k_rmsnorm<<<M, 256, 0, stream>>>(hidden, ln2, h);
  // 8) SwiGLU MLP + residual (silu*u fused into the Wu GEMM epilogue)
  k_wtrans<<<dim3(DFF_ / 32, 2048 / 32), 256, 0, stream>>>(Wg, wt, 2048, DFF_);
  k_gemm<0><<<dim3(DFF_ / 128, M / 128), 256, 0, stream>>>(h, wt, g, nullptr, nullptr, M, DFF_, 2048);
  k_wtrans<<<dim3(DFF_ / 32, 2048 / 32), 256, 0, stream>>>(Wu, wt, 2048, DFF_);
  k_gemm<2><<<dim3(DFF_ / 128, M / 128), 256, 0, stream>>>(h, wt, g, nullptr, g, M, DFF_, 2048);
  k_wtrans<<<dim3(2048 / 32, DFF_ / 32), 256, 0, stream>>>(Wd, wt, DFF_, 2048);
  k_gemm<1><<<dim3(2048 / 128, M / 128), 256, 0, stream>>>(g, wt, (float*)d_out, hidden, nullptr, M, 2048, DFF_);
}